// Round 1
// baseline (1354.466 us; speedup 1.0000x reference)
//
#include <hip/hip_runtime.h>
#include <hip/hip_bf16.h>

// ============================================================================
// ASTRAMoE fused implementation, round 1.
//   - gate path (topk-critical) in fp32 vector math
//   - experts + alpha head in bf16 MFMA (16x16x32), fp32 accumulate
// d_out layout (fp32): logits[N*10] | alpha[N*10] | gate_weights[N*4] | load[4]
// ws layout: W1T bf16 [5][256][256] | W2F bf16 [5][4096] | load partials f32 [4096][4]
// ============================================================================

typedef short bf8v __attribute__((ext_vector_type(8)));   // 8 bf16 bit patterns (4 VGPR)
typedef float f32x4v __attribute__((ext_vector_type(4)));

static constexpr int    NTOK      = 262144;
static constexpr size_t ALPHA_OFF = (size_t)NTOK * 10;
static constexpr size_t GW_OFF    = (size_t)2 * NTOK * 10;
static constexpr size_t LOAD_OFF  = GW_OFF + (size_t)NTOK * 4;

static constexpr size_t W1T_OFF_B   = 0;          // 5*65536 bf16 = 655360 B
static constexpr size_t W2F_OFF_B   = 655360;     // 5*4096  bf16 = 40960 B
static constexpr size_t LPART_OFF_B = 696320;     // 4096*4 f32   = 65536 B

__device__ __forceinline__ float gelu_f(float v){
  return 0.5f * v * (1.0f + erff(v * 0.7071067811865475f));
}
__device__ __forceinline__ float softplus_f(float v){
  return (v > 20.0f) ? v : log1pf(expf(v));
}
__device__ __forceinline__ unsigned short f2bf(float f){   // RNE f32 -> bf16 bits
  unsigned int u = __float_as_uint(f);
  unsigned int r = (u + 0x7fffu + ((u >> 16) & 1u)) >> 16;
  return (unsigned short)r;
}
__device__ __forceinline__ f32x4v mfma16(bf8v a, bf8v b, f32x4v c){
  return __builtin_amdgcn_mfma_f32_16x16x32_bf16(a, b, c, 0, 0, 0);
}

// ---------------------------------------------------------------------------
// prep: W1T[e][h][d] = (e<4 ? We1[e][d][h] : Wa1[d][h]) as bf16
// ---------------------------------------------------------------------------
__global__ void prep_w1t(const float* __restrict__ We1, const float* __restrict__ Wa1,
                         unsigned short* __restrict__ W1T){
  int idx = blockIdx.x * 256 + threadIdx.x;          // < 5*65536
  int e = idx >> 16;
  int rem = idx & 65535;
  int h = rem >> 8, d = rem & 255;
  float v = (e < 4) ? We1[(e << 16) + (d << 8) + h] : Wa1[(d << 8) + h];
  W1T[idx] = f2bf(v);
}

// prep: W2F frag-linear: [e][kc2][lane][jj] = W2[e][h=32*kc2+8*(lane>>4)+jj][c=lane&15]
__global__ void prep_w2f(const float* __restrict__ We2, const float* __restrict__ Wa2,
                         unsigned short* __restrict__ W2F){
  int idx = blockIdx.x * 256 + threadIdx.x;          // < 5*4096
  int e = idx >> 12;
  int rem = idx & 4095;
  int kc2 = rem >> 9;
  int l   = (rem >> 3) & 63;
  int jj  = rem & 7;
  int hh  = kc2 * 32 + ((l >> 4) << 3) + jj;
  int c   = l & 15;
  float v = 0.0f;
  if (c < 10) v = (e < 4) ? We2[e * 2560 + hh * 10 + c] : Wa2[hh * 10 + c];
  W2F[idx] = f2bf(v);
}

// ---------------------------------------------------------------------------
// gate kernel: fp32, 64 tokens/block, 256 threads (4 waves).
// wave w: tokens [16w,16w+16); thread (lane): outs [4*lane, 4*lane+4), all 16 tokens.
// ---------------------------------------------------------------------------
__global__ __launch_bounds__(256, 2) void gate_kernel(
    const float* __restrict__ x,   const float* __restrict__ Wg1,
    const float* __restrict__ bg1, const float* __restrict__ Wg2,
    const float* __restrict__ bg2, float* __restrict__ out,
    float* __restrict__ lpart){
  __shared__ float xs[64 * 256];
  __shared__ float wsum[4][4];
  int tid = threadIdx.x;
  size_t t0 = (size_t)blockIdx.x * 64;

  #pragma unroll
  for (int r = 0; r < 16; ++r){
    int f = r * 1024 + tid * 4;
    int t = f >> 8, k = f & 255;
    *(float4*)&xs[t * 256 + k] = *(const float4*)&x[(t0 + t) * 256 + k];
  }
  __syncthreads();

  int w = tid >> 6, lane = tid & 63;
  int o0 = lane * 4;
  int tb = w * 16;

  float acc[16][4];
  #pragma unroll
  for (int t = 0; t < 16; ++t){
    acc[t][0] = 0.f; acc[t][1] = 0.f; acc[t][2] = 0.f; acc[t][3] = 0.f;
  }

  for (int k = 0; k < 256; k += 4){
    float4 wf0 = *(const float4*)&Wg1[(size_t)(k + 0) * 256 + o0];
    float4 wf1 = *(const float4*)&Wg1[(size_t)(k + 1) * 256 + o0];
    float4 wf2 = *(const float4*)&Wg1[(size_t)(k + 2) * 256 + o0];
    float4 wf3 = *(const float4*)&Wg1[(size_t)(k + 3) * 256 + o0];
    #pragma unroll
    for (int t = 0; t < 16; ++t){
      float4 xv = *(const float4*)&xs[(tb + t) * 256 + k];
      acc[t][0] += xv.x * wf0.x; acc[t][1] += xv.x * wf0.y; acc[t][2] += xv.x * wf0.z; acc[t][3] += xv.x * wf0.w;
      acc[t][0] += xv.y * wf1.x; acc[t][1] += xv.y * wf1.y; acc[t][2] += xv.y * wf1.z; acc[t][3] += xv.y * wf1.w;
      acc[t][0] += xv.z * wf2.x; acc[t][1] += xv.z * wf2.y; acc[t][2] += xv.z * wf2.z; acc[t][3] += xv.z * wf2.w;
      acc[t][0] += xv.w * wf3.x; acc[t][1] += xv.w * wf3.y; acc[t][2] += xv.w * wf3.z; acc[t][3] += xv.w * wf3.w;
    }
  }

  // second layer: partial glog over this thread's 4 hidden dims
  float4 b1v = *(const float4*)&bg1[o0];
  float4 w20 = *(const float4*)&Wg2[(o0 + 0) * 4];
  float4 w21 = *(const float4*)&Wg2[(o0 + 1) * 4];
  float4 w22 = *(const float4*)&Wg2[(o0 + 2) * 4];
  float4 w23 = *(const float4*)&Wg2[(o0 + 3) * 4];
  float part[16][4];
  #pragma unroll
  for (int t = 0; t < 16; ++t){
    float g0 = gelu_f(acc[t][0] + b1v.x);
    float g1 = gelu_f(acc[t][1] + b1v.y);
    float g2 = gelu_f(acc[t][2] + b1v.z);
    float g3 = gelu_f(acc[t][3] + b1v.w);
    part[t][0] = g0 * w20.x + g1 * w21.x + g2 * w22.x + g3 * w23.x;
    part[t][1] = g0 * w20.y + g1 * w21.y + g2 * w22.y + g3 * w23.y;
    part[t][2] = g0 * w20.z + g1 * w21.z + g2 * w22.z + g3 * w23.z;
    part[t][3] = g0 * w20.w + g1 * w21.w + g2 * w22.w + g3 * w23.w;
  }
  // butterfly reduce across 64 lanes (all lanes end with full sums)
  #pragma unroll
  for (int m = 1; m < 64; m <<= 1){
    #pragma unroll
    for (int t = 0; t < 16; ++t){
      part[t][0] += __shfl_xor(part[t][0], m, 64);
      part[t][1] += __shfl_xor(part[t][1], m, 64);
      part[t][2] += __shfl_xor(part[t][2], m, 64);
      part[t][3] += __shfl_xor(part[t][3], m, 64);
    }
  }

  float wv0 = 0.f, wv1 = 0.f, wv2 = 0.f, wv3 = 0.f;
  if (lane < 16){
    // pick this lane's token values without runtime register indexing
    float v0 = 0.f, v1 = 0.f, v2 = 0.f, v3 = 0.f;
    #pragma unroll
    for (int t = 0; t < 16; ++t){
      if (lane == t){ v0 = part[t][0]; v1 = part[t][1]; v2 = part[t][2]; v3 = part[t][3]; }
    }
    v0 += bg2[0]; v1 += bg2[1]; v2 += bg2[2]; v3 += bg2[3];
    // top-1 (lowest index wins ties)
    float m1 = fmaxf(fmaxf(v0, v1), fmaxf(v2, v3));
    int i1 = (v0 == m1) ? 0 : (v1 == m1) ? 1 : (v2 == m1) ? 2 : 3;
    // top-2 among remaining (scan order, strict >)
    float m2 = 0.f; int i2 = -1;
    if (0 != i1){ m2 = v0; i2 = 0; }
    if (1 != i1 && (i2 < 0 || v1 > m2)){ m2 = v1; i2 = 1; }
    if (2 != i1 && (i2 < 0 || v2 > m2)){ m2 = v2; i2 = 2; }
    if (3 != i1 && (i2 < 0 || v3 > m2)){ m2 = v3; i2 = 3; }
    float mm = fmaxf(m1, 0.0f);
    float s0 = (0 == i1 || 0 == i2) ? v0 : 0.0f;
    float s1 = (1 == i1 || 1 == i2) ? v1 : 0.0f;
    float s2 = (2 == i1 || 2 == i2) ? v2 : 0.0f;
    float s3 = (3 == i1 || 3 == i2) ? v3 : 0.0f;
    wv0 = expf(s0 - mm); wv1 = expf(s1 - mm); wv2 = expf(s2 - mm); wv3 = expf(s3 - mm);
    float inv = 1.0f / (wv0 + wv1 + wv2 + wv3);
    wv0 *= inv; wv1 *= inv; wv2 *= inv; wv3 *= inv;
    size_t t = t0 + tb + lane;
    float4 o4; o4.x = wv0; o4.y = wv1; o4.z = wv2; o4.w = wv3;
    *(float4*)&out[GW_OFF + t * 4] = o4;
  }
  // load partials: sum wv over lanes (lanes >=16 contribute 0)
  #pragma unroll
  for (int m = 1; m < 64; m <<= 1){
    wv0 += __shfl_xor(wv0, m, 64);
    wv1 += __shfl_xor(wv1, m, 64);
    wv2 += __shfl_xor(wv2, m, 64);
    wv3 += __shfl_xor(wv3, m, 64);
  }
  if (lane == 0){ wsum[w][0] = wv0; wsum[w][1] = wv1; wsum[w][2] = wv2; wsum[w][3] = wv3; }
  __syncthreads();
  if (tid < 4){
    lpart[(size_t)blockIdx.x * 4 + tid] =
        wsum[0][tid] + wsum[1][tid] + wsum[2][tid] + wsum[3][tid];
  }
}

// deterministic tree reduce of 4096x4 partials -> load[4]
__global__ void reduce_load(const float* __restrict__ lpart, float* __restrict__ out){
  __shared__ float red[64][4];
  int tid = threadIdx.x;
  int e = tid & 3, ch = tid >> 2;
  float s = 0.0f;
  for (int i = 0; i < 64; ++i) s += lpart[(size_t)(ch * 64 + i) * 4 + e];
  red[ch][e] = s;
  __syncthreads();
  if (tid < 4){
    float t = 0.0f;
    for (int c = 0; c < 64; ++c) t += red[c][tid];
    out[LOAD_OFF + tid] = t;
  }
}

// ---------------------------------------------------------------------------
// experts + alpha: bf16 MFMA. 64 tokens/block, 256 threads (4 waves).
// layer1: C[64 tok][256 h]; wave w owns h-tiles 4w..4w+3, all 4 token-tiles.
// A-frags (x bf16) in registers, B staged frag-linear in LDS (double buffered).
// layer2 via h in LDS; epilogue fuses gate weighting / softplus.
// ---------------------------------------------------------------------------
__device__ __forceinline__ void stage_b1(const unsigned short* __restrict__ W1T,
                                         int e, int kc, unsigned short* __restrict__ buf,
                                         int tid){
  #pragma unroll
  for (int j = 0; j < 4; ++j){
    int f = tid + j * 256;                 // frag id = ot*64 + ll
    int ot = f >> 6, ll = f & 63;
    int row = ot * 16 + (ll & 15);
    int col = kc * 32 + ((ll >> 4) << 3);
    *(bf8v*)&buf[f * 8] = *(const bf8v*)&W1T[(e << 16) + (row << 8) + col];
  }
}

__global__ __launch_bounds__(256, 2) void expert_kernel(
    const float* __restrict__ x, const unsigned short* __restrict__ W1T,
    const unsigned short* __restrict__ W2F, const float* __restrict__ be1,
    const float* __restrict__ ba1, const float* __restrict__ be2,
    const float* __restrict__ ba2, float* __restrict__ out){
  __shared__ unsigned short bbuf[2][8192];       // 2 x 16 KB frag-linear B chunks
  __shared__ unsigned short hs[64 * 264];        // h tile, padded rows (conflict-free b128)
  int tid = threadIdx.x;
  int w = tid >> 6, l = tid & 63;
  int l15 = l & 15, lq = l >> 4;
  size_t t0 = (size_t)blockIdx.x * 64;

  // A-fragments: x[64][256] -> bf16, held in registers (4 tt x 8 kc)
  bf8v afrag[4][8];
  #pragma unroll
  for (int tt = 0; tt < 4; ++tt){
    const float* xrow = x + (t0 + tt * 16 + l15) * 256;
    #pragma unroll
    for (int kc = 0; kc < 8; ++kc){
      float4 p0 = *(const float4*)&xrow[kc * 32 + lq * 8];
      float4 p1 = *(const float4*)&xrow[kc * 32 + lq * 8 + 4];
      bf8v a;
      a[0] = (short)f2bf(p0.x); a[1] = (short)f2bf(p0.y);
      a[2] = (short)f2bf(p0.z); a[3] = (short)f2bf(p0.w);
      a[4] = (short)f2bf(p1.x); a[5] = (short)f2bf(p1.y);
      a[6] = (short)f2bf(p1.z); a[7] = (short)f2bf(p1.w);
      afrag[tt][kc] = a;
    }
  }

  f32x4v lacc; lacc[0] = 0.f; lacc[1] = 0.f; lacc[2] = 0.f; lacc[3] = 0.f;

  for (int e = 0; e < 5; ++e){
    f32x4v acc[4][4];
    #pragma unroll
    for (int a1 = 0; a1 < 4; ++a1)
      #pragma unroll
      for (int b1 = 0; b1 < 4; ++b1){
        acc[a1][b1][0] = 0.f; acc[a1][b1][1] = 0.f;
        acc[a1][b1][2] = 0.f; acc[a1][b1][3] = 0.f;
      }

    stage_b1(W1T, e, 0, bbuf[0], tid);
    __syncthreads();
    #pragma unroll
    for (int kc = 0; kc < 8; ++kc){
      if (kc < 7) stage_b1(W1T, e, kc + 1, bbuf[(kc + 1) & 1], tid);
      const unsigned short* bb = bbuf[kc & 1];
      #pragma unroll
      for (int i = 0; i < 4; ++i){
        int ot = w * 4 + i;
        bf8v bf = *(const bf8v*)&bb[(ot * 64 + l) * 8];
        #pragma unroll
        for (int tt = 0; tt < 4; ++tt)
          acc[tt][i] = mfma16(afrag[tt][kc], bf, acc[tt][i]);
      }
      __syncthreads();
    }

    // epilogue L1: + be1, GELU, -> hs (bf16)
    const float* b1p = (e < 4) ? (be1 + e * 256) : ba1;
    #pragma unroll
    for (int i = 0; i < 4; ++i){
      int hcol = (w * 4 + i) * 16 + l15;
      float bv = b1p[hcol];
      #pragma unroll
      for (int tt = 0; tt < 4; ++tt){
        #pragma unroll
        for (int r = 0; r < 4; ++r){
          int trow = tt * 16 + lq * 4 + r;
          hs[trow * 264 + hcol] = f2bf(gelu_f(acc[tt][i][r] + bv));
        }
      }
    }
    __syncthreads();

    // stage B2 frag-linear (8 KB contiguous copy)
    #pragma unroll
    for (int j = 0; j < 2; ++j){
      int f = tid + j * 256;
      *(bf8v*)&bbuf[0][f * 8] = *(const bf8v*)&W2F[e * 4096 + f * 8];
    }
    __syncthreads();

    // layer2: wave w handles token-tile w
    f32x4v d2; d2[0] = 0.f; d2[1] = 0.f; d2[2] = 0.f; d2[3] = 0.f;
    #pragma unroll
    for (int kc2 = 0; kc2 < 8; ++kc2){
      bf8v a2 = *(const bf8v*)&hs[(w * 16 + l15) * 264 + kc2 * 32 + lq * 8];
      bf8v b2 = *(const bf8v*)&bbuf[0][(kc2 * 64 + l) * 8];
      d2 = mfma16(a2, b2, d2);
    }
    __syncthreads();

    if (e < 4){
      float bcol = (l15 < 10) ? be2[e * 10 + l15] : 0.0f;
      #pragma unroll
      for (int r = 0; r < 4; ++r){
        size_t t = t0 + w * 16 + lq * 4 + r;
        float gwv = out[GW_OFF + t * 4 + e];
        lacc[r] += gwv * (d2[r] + bcol);
      }
    } else {
      if (l15 < 10){
        float bcol = ba2[l15];
        #pragma unroll
        for (int r = 0; r < 4; ++r){
          size_t t = t0 + w * 16 + lq * 4 + r;
          out[ALPHA_OFF + t * 10 + l15] = softplus_f(d2[r] + bcol) + 1e-6f;
        }
      }
    }
  }

  if (l15 < 10){
    #pragma unroll
    for (int r = 0; r < 4; ++r){
      size_t t = t0 + w * 16 + lq * 4 + r;
      out[t * 10 + l15] = lacc[r];
    }
  }
}

// ---------------------------------------------------------------------------
extern "C" void kernel_launch(void* const* d_in, const int* in_sizes, int n_in,
                              void* d_out, int out_size, void* d_ws, size_t ws_size,
                              hipStream_t stream){
  const float* x   = (const float*)d_in[0];
  const float* Wg1 = (const float*)d_in[1];
  const float* bg1 = (const float*)d_in[2];
  const float* Wg2 = (const float*)d_in[3];
  const float* bg2 = (const float*)d_in[4];
  const float* We1 = (const float*)d_in[5];
  const float* be1 = (const float*)d_in[6];
  const float* We2 = (const float*)d_in[7];
  const float* be2 = (const float*)d_in[8];
  const float* Wa1 = (const float*)d_in[9];
  const float* ba1 = (const float*)d_in[10];
  const float* Wa2 = (const float*)d_in[11];
  const float* ba2 = (const float*)d_in[12];
  float* out = (float*)d_out;

  unsigned short* W1T = (unsigned short*)((char*)d_ws + W1T_OFF_B);
  unsigned short* W2F = (unsigned short*)((char*)d_ws + W2F_OFF_B);
  float* lpart        = (float*)((char*)d_ws + LPART_OFF_B);

  hipLaunchKernelGGL(prep_w1t, dim3(1280), dim3(256), 0, stream, We1, Wa1, W1T);
  hipLaunchKernelGGL(prep_w2f, dim3(80),   dim3(256), 0, stream, We2, Wa2, W2F);
  hipLaunchKernelGGL(gate_kernel, dim3(4096), dim3(256), 0, stream,
                     x, Wg1, bg1, Wg2, bg2, out, lpart);
  hipLaunchKernelGGL(reduce_load, dim3(1), dim3(256), 0, stream, lpart, out);
  hipLaunchKernelGGL(expert_kernel, dim3(4096), dim3(256), 0, stream,
                     x, W1T, W2F, be1, ba1, be2, ba2, out);
}

// Round 2
// 991.606 us; speedup vs baseline: 1.3659x; 1.3659x over previous
//
#include <hip/hip_runtime.h>
#include <hip/hip_bf16.h>

// ============================================================================
// ASTRAMoE v2: everything on fp16 MFMA (16x16x32), fp32 accumulate.
//   gate:   fp16 MFMA approx -> flag near-ties (gap < 0.03) -> exact fp32
//           refine pass for flagged tokens only (erf-GELU, R1 top-k logic).
//   expert: fused 5-slot (4 experts + alpha head) swapped-operand kernel,
//           x staged once to LDS fp16 (XOR-swizzled), W1 frag-linear dbuf,
//           h^T via swizzled LDS, L2 + gate-weighting + softplus in-register.
// d_out (fp32): logits[N*10] | alpha[N*10] | gate_weights[N*4] | load[4]
// ============================================================================

typedef _Float16 f16x8 __attribute__((ext_vector_type(8)));
typedef _Float16 f16x4 __attribute__((ext_vector_type(4)));
typedef float    f32x4 __attribute__((ext_vector_type(4)));

static constexpr int    NTOK      = 262144;
static constexpr size_t ALPHA_OFF = (size_t)NTOK * 10;
static constexpr size_t GW_OFF    = (size_t)2 * NTOK * 10;
static constexpr size_t LOAD_OFF  = GW_OFF + (size_t)NTOK * 4;

// ws layout (bytes)
static constexpr size_t W1F_OFF   = 0;                 // 6*65536 halfs = 786432
static constexpr size_t W2F_OFF   = 786432;            // 6*4096 halfs  = 49152
static constexpr size_t FLAG_OFF  = 835584;            // 262144 u32    = 1 MB
static constexpr size_t LPART_OFF = 1884160;           // 1024*4 f32    = 16 KB

static constexpr float DELTA = 0.03f;   // refine threshold on 2nd-3rd logit gap

__device__ __forceinline__ float gelu_exact(float v){
  return 0.5f * v * (1.0f + erff(v * 0.7071067811865475f));
}
// tanh-approx GELU: v * sigmoid(2*0.79788456*(v + 0.044715 v^3)); |err| ~1e-3
__device__ __forceinline__ float gelu_fast(float v){
  float t = v * v;
  float p = __builtin_fmaf(0.0713548162726f, t, 1.5957691216057f);
  float z = __expf(v * p);
  float r = __builtin_amdgcn_rcpf(z + 1.0f);
  return v - v * r;
}
__device__ __forceinline__ float softplus_fast(float v){
  float z = __expf(v);
  float l = __logf(1.0f + z);
  return (v > 15.0f) ? v : l;
}
__device__ __forceinline__ f32x4 mfma16(f16x8 a, f16x8 b, f32x4 c){
  return __builtin_amdgcn_mfma_f32_16x16x32_f16(a, b, c, 0, 0, 0);
}

// exact top-2 (lowest index wins ties, matches jax.lax.top_k) + scatter-softmax
__device__ __forceinline__ void topk_softmax(float v0, float v1, float v2, float v3,
                                             float4& gw, float& gap){
  float m1 = fmaxf(fmaxf(v0, v1), fmaxf(v2, v3));
  int i1 = (v0 == m1) ? 0 : (v1 == m1) ? 1 : (v2 == m1) ? 2 : 3;
  float m2 = 0.f; int i2 = -1;
  if (0 != i1){ m2 = v0; i2 = 0; }
  if (1 != i1 && (i2 < 0 || v1 > m2)){ m2 = v1; i2 = 1; }
  if (2 != i1 && (i2 < 0 || v2 > m2)){ m2 = v2; i2 = 2; }
  if (3 != i1 && (i2 < 0 || v3 > m2)){ m2 = v3; i2 = 3; }
  float m3 = -3.0e38f;
  if (0 != i1 && 0 != i2) m3 = fmaxf(m3, v0);
  if (1 != i1 && 1 != i2) m3 = fmaxf(m3, v1);
  if (2 != i1 && 2 != i2) m3 = fmaxf(m3, v2);
  if (3 != i1 && 3 != i2) m3 = fmaxf(m3, v3);
  gap = m2 - m3;
  float mm = fmaxf(m1, 0.0f);
  float s0 = (0 == i1 || 0 == i2) ? v0 : 0.0f;
  float s1 = (1 == i1 || 1 == i2) ? v1 : 0.0f;
  float s2 = (2 == i1 || 2 == i2) ? v2 : 0.0f;
  float s3 = (3 == i1 || 3 == i2) ? v3 : 0.0f;
  float e0 = expf(s0 - mm), e1 = expf(s1 - mm), e2 = expf(s2 - mm), e3 = expf(s3 - mm);
  float inv = 1.0f / (e0 + e1 + e2 + e3);
  gw.x = e0 * inv; gw.y = e1 * inv; gw.z = e2 * inv; gw.w = e3 * inv;
}

// ---------------------------------------------------------------------------
// prep: W1F frag-linear fp16 A-layout: [e(6)][kc(8)][ht(16)][lane(64)][8]
//   value = W1^T[h = ht*16 + (l&15)][d = kc*32 + (l>>4)*8 + j]
//   e 0..3 = We1, e=4 = Wa1, e=5 = Wg1
// ---------------------------------------------------------------------------
__global__ void prep_w1f(const float* __restrict__ We1, const float* __restrict__ Wa1,
                         const float* __restrict__ Wg1, _Float16* __restrict__ W1F){
  int idx = blockIdx.x * 256 + threadIdx.x;          // < 49152
  int e = idx >> 13;
  int r = idx & 8191;
  int kc = r >> 10;
  int entry = r & 1023;
  int ht = entry >> 6, ll = entry & 63;
  int h = ht * 16 + (ll & 15);
  int d0 = kc * 32 + ((ll >> 4) << 3);
  f16x8 o;
  #pragma unroll
  for (int j = 0; j < 8; ++j){
    int d = d0 + j;
    float v;
    if (e < 4)       v = We1[e * 65536 + d * 256 + h];
    else if (e == 4) v = Wa1[d * 256 + h];
    else             v = Wg1[d * 256 + h];
    o[j] = (_Float16)v;
  }
  *(f16x8*)&W1F[(size_t)idx * 8] = o;
}

// prep: W2F frag-linear fp16 A-layout: [e(6)][kc2(8)][lane(64)][8]
//   value = W2[h = kc2*32 + (l>>4)*8 + j][c = l&15], zero-padded
__global__ void prep_w2f(const float* __restrict__ We2, const float* __restrict__ Wa2,
                         const float* __restrict__ Wg2, _Float16* __restrict__ W2F){
  int idx = blockIdx.x * 256 + threadIdx.x;          // < 3072
  int e = idx >> 9;
  int r = idx & 511;
  int k2 = r >> 6, ll = r & 63;
  int c = ll & 15;
  int h0 = k2 * 32 + ((ll >> 4) << 3);
  f16x8 o;
  #pragma unroll
  for (int j = 0; j < 8; ++j){
    int h = h0 + j;
    float v = 0.0f;
    if (e < 4){ if (c < 10) v = We2[e * 2560 + h * 10 + c]; }
    else if (e == 4){ if (c < 10) v = Wa2[h * 10 + c]; }
    else { if (c < 4) v = Wg2[h * 4 + c]; }
    o[j] = (_Float16)v;
  }
  *(f16x8*)&W2F[(size_t)idx * 8] = o;
}

// ---------------------------------------------------------------------------
// main fused kernel. 512 threads (8 waves), 128 tokens/block, 2048 blocks.
// wave w: hg = w>>1 owns h rows [hg*64, hg*64+64); tg = w&1 owns tokens
// [tg*64, tg*64+64) of the block. L1 swapped: C1[h][tok] = W1 @ x^T.
// LDS: xs 64 KB (swizzled [128][256] f16) | w1b 2x16 KB frag-linear |
//      hsT 32 KB (swizzled [64][256] f16, one token-phase at a time)
// ---------------------------------------------------------------------------
__device__ __forceinline__ void stage_w1(const _Float16* __restrict__ W1F,
                                         int e, int kc, _Float16* __restrict__ dst,
                                         int tid){
  const f16x8* s = (const f16x8*)(W1F + (size_t)(e * 8 + kc) * 8192);
  f16x8* d = (f16x8*)dst;
  d[tid] = s[tid];
  d[tid + 512] = s[tid + 512];
}

template<bool IS_GATE>
__global__ __launch_bounds__(512, 1) void main_kernel(
    const float* __restrict__ x,
    const _Float16* __restrict__ W1F, const _Float16* __restrict__ W2F,
    const float* __restrict__ bg1, const float* __restrict__ bg2,
    const float* __restrict__ be1, const float* __restrict__ be2,
    const float* __restrict__ ba1, const float* __restrict__ ba2,
    float* __restrict__ out, unsigned int* __restrict__ flags){
  __shared__ __align__(16) unsigned char lds[131072];
  unsigned char* xsb  = lds;            // 64 KB
  _Float16*      w1b  = (_Float16*)(lds + 65536);   // 2 x 16 KB
  unsigned char* hsb  = lds + 98304;    // 32 KB

  const int tid = threadIdx.x;
  const int w = tid >> 6, l = tid & 63;
  const int l15 = l & 15, lq = l >> 4;
  const int hg = w >> 1, tg = w & 1;
  const size_t t0 = (size_t)blockIdx.x * 128;
  const int tile = (tg ? 4 : 0) + hg;   // this wave's L2/epilogue token-tile

  // ---- stage x -> fp16, swizzled rows [tok][256] (row = 512 B) ----
  {
    int tok = tid >> 2, seg = tid & 3;
    const float* xr = x + (t0 + tok) * 256 + seg * 64;
    int key = (tok & 7) << 4;
    #pragma unroll
    for (int q = 0; q < 8; ++q){
      float4 f0 = *(const float4*)(xr + q * 8);
      float4 f1 = *(const float4*)(xr + q * 8 + 4);
      f16x8 h;
      h[0] = (_Float16)f0.x; h[1] = (_Float16)f0.y;
      h[2] = (_Float16)f0.z; h[3] = (_Float16)f0.w;
      h[4] = (_Float16)f1.x; h[5] = (_Float16)f1.y;
      h[6] = (_Float16)f1.z; h[7] = (_Float16)f1.w;
      *(f16x8*)(xsb + tok * 512 + ((seg * 128 + q * 16) ^ key)) = h;
    }
  }

  float4 gw4 = {0,0,0,0};
  if (!IS_GATE)
    gw4 = *(const float4*)&out[GW_OFF + (t0 + tile * 16 + l15) * 4];
  f32x4 lacc = {0,0,0,0};

  const int NE = IS_GATE ? 1 : 5;
  for (int ee = 0; ee < NE; ++ee){
    const int e = IS_GATE ? 5 : ee;
    f32x4 acc[4][4];
    #pragma unroll
    for (int i = 0; i < 4; ++i)
      #pragma unroll
      for (int tt = 0; tt < 4; ++tt){
        acc[i][tt][0]=0.f; acc[i][tt][1]=0.f; acc[i][tt][2]=0.f; acc[i][tt][3]=0.f;
      }

    stage_w1(W1F, e, 0, w1b, tid);
    __syncthreads();
    for (int kc = 0; kc < 8; ++kc){
      if (kc < 7) stage_w1(W1F, e, kc + 1, w1b + ((kc + 1) & 1) * 8192, tid);
      const _Float16* wb = w1b + (kc & 1) * 8192;
      f16x8 af[4], bf[4];
      #pragma unroll
      for (int i = 0; i < 4; ++i)
        af[i] = *(const f16x8*)&wb[((hg * 4 + i) * 64 + l) * 8];
      #pragma unroll
      for (int tt = 0; tt < 4; ++tt){
        int ltok = (tg * 4 + tt) * 16 + l15;
        bf[tt] = *(const f16x8*)(xsb + ltok * 512 +
                   ((kc * 64 + lq * 16) ^ ((ltok & 7) << 4)));
      }
      #pragma unroll
      for (int i = 0; i < 4; ++i)
        #pragma unroll
        for (int tt = 0; tt < 4; ++tt)
          acc[i][tt] = mfma16(af[i], bf[tt], acc[i][tt]);
      __syncthreads();
    }

    // ---- bias + GELU -> hsT -> L2, in 2 token-phases ----
    const float* b1 = IS_GATE ? bg1 : (e < 4 ? be1 + e * 256 : ba1);
    for (int ph = 0; ph < 2; ++ph){
      if (tg == ph){
        #pragma unroll
        for (int i = 0; i < 4; ++i){
          int h0 = (hg * 4 + i) * 16 + lq * 4;
          float4 b4 = *(const float4*)&b1[h0];
          #pragma unroll
          for (int tt = 0; tt < 4; ++tt){
            f16x4 hv;
            hv[0] = (_Float16)gelu_fast(acc[i][tt][0] + b4.x);
            hv[1] = (_Float16)gelu_fast(acc[i][tt][1] + b4.y);
            hv[2] = (_Float16)gelu_fast(acc[i][tt][2] + b4.z);
            hv[3] = (_Float16)gelu_fast(acc[i][tt][3] + b4.w);
            int ltok = tt * 16 + l15;
            *(f16x4*)(hsb + ltok * 512 +
                      ((h0 * 2) ^ ((ltok & 7) << 4))) = hv;
          }
        }
      }
      __syncthreads();
      if (tg == ph){
        // L2 for this wave's tile (local tile index = hg)
        f32x4 d2 = {0,0,0,0};
        int ltok = hg * 16 + l15;
        int key = (ltok & 7) << 4;
        #pragma unroll
        for (int k2 = 0; k2 < 8; ++k2){
          f16x8 a2 = *(const f16x8*)&W2F[((size_t)(e * 8 + k2) * 64 + l) * 8];
          f16x8 b2 = *(const f16x8*)(hsb + ltok * 512 +
                       ((k2 * 64 + lq * 16) ^ key));
          d2 = mfma16(a2, b2, d2);
        }
        size_t t = t0 + tile * 16 + l15;
        if (IS_GATE){
          if (lq == 0){
            float v0 = d2[0] + bg2[0], v1 = d2[1] + bg2[1];
            float v2 = d2[2] + bg2[2], v3 = d2[3] + bg2[3];
            float4 gw; float gap;
            topk_softmax(v0, v1, v2, v3, gw, gap);
            *(float4*)&out[GW_OFF + t * 4] = gw;
            flags[t] = (gap < DELTA) ? 1u : 0u;
          }
        } else if (e < 4){
          float gwv = (e == 0) ? gw4.x : (e == 1) ? gw4.y : (e == 2) ? gw4.z : gw4.w;
          #pragma unroll
          for (int r = 0; r < 4; ++r){
            int c = 4 * lq + r;
            float bv = (c < 10) ? be2[e * 10 + c] : 0.0f;
            lacc[r] += gwv * (d2[r] + bv);
          }
        } else {
          #pragma unroll
          for (int r = 0; r < 4; ++r){
            int c = 4 * lq + r;
            if (c < 10)
              out[ALPHA_OFF + t * 10 + c] = softplus_fast(d2[r] + ba2[c]) + 1e-6f;
          }
        }
      }
      __syncthreads();
    }
  }

  if (!IS_GATE){
    size_t t = t0 + tile * 16 + l15;
    #pragma unroll
    for (int r = 0; r < 4; ++r){
      int c = 4 * lq + r;
      if (c < 10) out[t * 10 + c] = lacc[r];
    }
  }
}

// ---------------------------------------------------------------------------
// refine: exact fp32 gate MLP (erf GELU) for flagged tokens. 1 wave/token.
// ---------------------------------------------------------------------------
__global__ __launch_bounds__(256) void refine_kernel(
    const float* __restrict__ x, const float* __restrict__ Wg1,
    const float* __restrict__ bg1, const float* __restrict__ Wg2,
    const float* __restrict__ bg2, const unsigned int* __restrict__ flags,
    float* __restrict__ out){
  int wglob = blockIdx.x * 4 + (threadIdx.x >> 6);
  int l = threadIdx.x & 63;
  int hb = l * 4;
  for (int t = wglob; t < NTOK; t += 2048){
    if (!flags[t]) continue;
    const float* xr = x + (size_t)t * 256;
    float h0 = 0.f, h1 = 0.f, h2 = 0.f, h3 = 0.f;
    #pragma unroll 4
    for (int d = 0; d < 256; ++d){
      float xv = xr[d];
      float4 wv = *(const float4*)&Wg1[d * 256 + hb];
      h0 = fmaf(xv, wv.x, h0); h1 = fmaf(xv, wv.y, h1);
      h2 = fmaf(xv, wv.z, h2); h3 = fmaf(xv, wv.w, h3);
    }
    float4 b4 = *(const float4*)&bg1[hb];
    h0 = gelu_exact(h0 + b4.x); h1 = gelu_exact(h1 + b4.y);
    h2 = gelu_exact(h2 + b4.z); h3 = gelu_exact(h3 + b4.w);
    float4 w0 = *(const float4*)&Wg2[(hb + 0) * 4];
    float4 w1 = *(const float4*)&Wg2[(hb + 1) * 4];
    float4 w2 = *(const float4*)&Wg2[(hb + 2) * 4];
    float4 w3 = *(const float4*)&Wg2[(hb + 3) * 4];
    float p0 = h0 * w0.x + h1 * w1.x + h2 * w2.x + h3 * w3.x;
    float p1 = h0 * w0.y + h1 * w1.y + h2 * w2.y + h3 * w3.y;
    float p2 = h0 * w0.z + h1 * w1.z + h2 * w2.z + h3 * w3.z;
    float p3 = h0 * w0.w + h1 * w1.w + h2 * w2.w + h3 * w3.w;
    #pragma unroll
    for (int m = 1; m < 64; m <<= 1){
      p0 += __shfl_xor(p0, m, 64); p1 += __shfl_xor(p1, m, 64);
      p2 += __shfl_xor(p2, m, 64); p3 += __shfl_xor(p3, m, 64);
    }
    if (l == 0){
      float4 gw; float gap;
      topk_softmax(p0 + bg2[0], p1 + bg2[1], p2 + bg2[2], p3 + bg2[3], gw, gap);
      *(float4*)&out[GW_OFF + (size_t)t * 4] = gw;
    }
  }
}

// ---------------------------------------------------------------------------
// load = sum of gate_weights over tokens (deterministic two-stage reduce)
// ---------------------------------------------------------------------------
__global__ void load_partial(const float* __restrict__ gw, float* __restrict__ lpart){
  __shared__ float4 ws4[4];
  int g = blockIdx.x * 256 + threadIdx.x;
  float4 v = *(const float4*)&gw[(size_t)g * 4];
  #pragma unroll
  for (int m = 1; m < 64; m <<= 1){
    v.x += __shfl_xor(v.x, m, 64); v.y += __shfl_xor(v.y, m, 64);
    v.z += __shfl_xor(v.z, m, 64); v.w += __shfl_xor(v.w, m, 64);
  }
  if ((threadIdx.x & 63) == 0) ws4[threadIdx.x >> 6] = v;
  __syncthreads();
  if (threadIdx.x == 0){
    float4 s;
    s.x = ws4[0].x + ws4[1].x + ws4[2].x + ws4[3].x;
    s.y = ws4[0].y + ws4[1].y + ws4[2].y + ws4[3].y;
    s.z = ws4[0].z + ws4[1].z + ws4[2].z + ws4[3].z;
    s.w = ws4[0].w + ws4[1].w + ws4[2].w + ws4[3].w;
    *(float4*)&lpart[blockIdx.x * 4] = s;
  }
}

__global__ void load_final(const float* __restrict__ lpart, float* __restrict__ out){
  __shared__ float4 ws4[4];
  int tid = threadIdx.x;
  const float4* lp = (const float4*)lpart;
  float4 v;
  v.x = lp[tid].x + lp[tid+256].x + lp[tid+512].x + lp[tid+768].x;
  v.y = lp[tid].y + lp[tid+256].y + lp[tid+512].y + lp[tid+768].y;
  v.z = lp[tid].z + lp[tid+256].z + lp[tid+512].z + lp[tid+768].z;
  v.w = lp[tid].w + lp[tid+256].w + lp[tid+512].w + lp[tid+768].w;
  #pragma unroll
  for (int m = 1; m < 64; m <<= 1){
    v.x += __shfl_xor(v.x, m, 64); v.y += __shfl_xor(v.y, m, 64);
    v.z += __shfl_xor(v.z, m, 64); v.w += __shfl_xor(v.w, m, 64);
  }
  if ((tid & 63) == 0) ws4[tid >> 6] = v;
  __syncthreads();
  if (tid == 0){
    float4 s;
    s.x = ws4[0].x + ws4[1].x + ws4[2].x + ws4[3].x;
    s.y = ws4[0].y + ws4[1].y + ws4[2].y + ws4[3].y;
    s.z = ws4[0].z + ws4[1].z + ws4[2].z + ws4[3].z;
    s.w = ws4[0].w + ws4[1].w + ws4[2].w + ws4[3].w;
    *(float4*)&out[LOAD_OFF] = s;
  }
}

// ---------------------------------------------------------------------------
extern "C" void kernel_launch(void* const* d_in, const int* in_sizes, int n_in,
                              void* d_out, int out_size, void* d_ws, size_t ws_size,
                              hipStream_t stream){
  const float* x   = (const float*)d_in[0];
  const float* Wg1 = (const float*)d_in[1];
  const float* bg1 = (const float*)d_in[2];
  const float* Wg2 = (const float*)d_in[3];
  const float* bg2 = (const float*)d_in[4];
  const float* We1 = (const float*)d_in[5];
  const float* be1 = (const float*)d_in[6];
  const float* We2 = (const float*)d_in[7];
  const float* be2 = (const float*)d_in[8];
  const float* Wa1 = (const float*)d_in[9];
  const float* ba1 = (const float*)d_in[10];
  const float* Wa2 = (const float*)d_in[11];
  const float* ba2 = (const float*)d_in[12];
  float* out = (float*)d_out;

  _Float16* W1F       = (_Float16*)((char*)d_ws + W1F_OFF);
  _Float16* W2F       = (_Float16*)((char*)d_ws + W2F_OFF);
  unsigned int* flags = (unsigned int*)((char*)d_ws + FLAG_OFF);
  float* lpart        = (float*)((char*)d_ws + LPART_OFF);

  hipLaunchKernelGGL(prep_w1f, dim3(192), dim3(256), 0, stream, We1, Wa1, Wg1, W1F);
  hipLaunchKernelGGL(prep_w2f, dim3(12),  dim3(256), 0, stream, We2, Wa2, Wg2, W2F);
  hipLaunchKernelGGL((main_kernel<true>), dim3(2048), dim3(512), 0, stream,
                     x, W1F, W2F, bg1, bg2, be1, be2, ba1, ba2, out, flags);
  hipLaunchKernelGGL(refine_kernel, dim3(512), dim3(256), 0, stream,
                     x, Wg1, bg1, Wg2, bg2, flags, out);
  hipLaunchKernelGGL(load_partial, dim3(1024), dim3(256), 0, stream,
                     out + GW_OFF, lpart);
  hipLaunchKernelGGL(load_final, dim3(1), dim3(256), 0, stream, lpart, out);
  hipLaunchKernelGGL((main_kernel<false>), dim3(2048), dim3(512), 0, stream,
                     x, W1F, W2F, bg1, bg2, be1, be2, ba1, ba2, out, flags);
}

// Round 3
// 727.862 us; speedup vs baseline: 1.8609x; 1.3624x over previous
//
#include <hip/hip_runtime.h>
#include <hip/hip_bf16.h>

// ============================================================================
// ASTRAMoE v3: single fused pass (gate + 4 experts + alpha), fp16 MFMA.
//   gate: L1 MFMA fp16, L2 + erf-GELU in fp32 registers -> exact-ish logits
//         (eps ~6e-4); flag gap<0.008 tokens, refine exactly after.
//   experts/alpha: L1 MFMA -> fast-GELU -> hs (LDS, overlaid on W1 dbuf) ->
//         L2 MFMA; gate weighting + softplus fused in-register.
// LDS 68KB -> 2 blocks/CU so barrier drains overlap across blocks.
// d_out (fp32): logits[N*10] | alpha[N*10] | gate_weights[N*4] | load[4]
// ============================================================================

typedef _Float16 f16x8 __attribute__((ext_vector_type(8)));
typedef _Float16 f16x4 __attribute__((ext_vector_type(4)));
typedef float    f32x4 __attribute__((ext_vector_type(4)));

static constexpr int    NTOK      = 262144;
static constexpr size_t ALPHA_OFF = (size_t)NTOK * 10;
static constexpr size_t GW_OFF    = (size_t)2 * NTOK * 10;
static constexpr size_t LOAD_OFF  = GW_OFF + (size_t)NTOK * 4;

// ws layout (bytes)
static constexpr size_t W1F_OFF   = 0;          // 6*65536 halfs = 786432
static constexpr size_t W2F_OFF   = 786432;     // 6*4096 halfs  = 49152
static constexpr size_t FLAG_OFF  = 835584;     // 262144 u8     = 256 KB
static constexpr size_t LPART_OFF = 1097728;    // 4096*4 f32    = 64 KB

static constexpr float DELTA = 0.008f;

__device__ __forceinline__ float gelu_exact(float v){
  return 0.5f * v * (1.0f + erff(v * 0.7071067811865475f));
}
__device__ __forceinline__ float gelu_fast(float v){
  float t = v * v;
  float p = __builtin_fmaf(0.0713548162726f, t, 1.5957691216057f);
  float z = __expf(v * p);
  float r = __builtin_amdgcn_rcpf(z + 1.0f);
  return v - v * r;
}
__device__ __forceinline__ float softplus_fast(float v){
  float z = __expf(v);
  float l = __logf(1.0f + z);
  return (v > 15.0f) ? v : l;
}
__device__ __forceinline__ f32x4 mfma16(f16x8 a, f16x8 b, f32x4 c){
  return __builtin_amdgcn_mfma_f32_16x16x32_f16(a, b, c, 0, 0, 0);
}

// exact top-2 (lowest index wins ties, matches jax.lax.top_k) + scatter-softmax
// NOTE: non-selected slots keep value 0.0 inside the softmax (reference does).
__device__ __forceinline__ void topk4(float v0, float v1, float v2, float v3,
                                      float4& gw, float& gap, int& i1, int& i2){
  float m1 = fmaxf(fmaxf(v0, v1), fmaxf(v2, v3));
  i1 = (v0 == m1) ? 0 : (v1 == m1) ? 1 : (v2 == m1) ? 2 : 3;
  float m2 = 0.f; i2 = -1;
  if (0 != i1){ m2 = v0; i2 = 0; }
  if (1 != i1 && (i2 < 0 || v1 > m2)){ m2 = v1; i2 = 1; }
  if (2 != i1 && (i2 < 0 || v2 > m2)){ m2 = v2; i2 = 2; }
  if (3 != i1 && (i2 < 0 || v3 > m2)){ m2 = v3; i2 = 3; }
  float m3 = -3.0e38f;
  if (0 != i1 && 0 != i2) m3 = fmaxf(m3, v0);
  if (1 != i1 && 1 != i2) m3 = fmaxf(m3, v1);
  if (2 != i1 && 2 != i2) m3 = fmaxf(m3, v2);
  if (3 != i1 && 3 != i2) m3 = fmaxf(m3, v3);
  gap = m2 - m3;
  float mm = fmaxf(m1, 0.0f);
  float s0 = (0 == i1 || 0 == i2) ? v0 : 0.0f;
  float s1 = (1 == i1 || 1 == i2) ? v1 : 0.0f;
  float s2 = (2 == i1 || 2 == i2) ? v2 : 0.0f;
  float s3 = (3 == i1 || 3 == i2) ? v3 : 0.0f;
  float e0 = expf(s0 - mm), e1 = expf(s1 - mm), e2 = expf(s2 - mm), e3 = expf(s3 - mm);
  float inv = 1.0f / (e0 + e1 + e2 + e3);
  gw.x = e0 * inv; gw.y = e1 * inv; gw.z = e2 * inv; gw.w = e3 * inv;
}

// ---------------------------------------------------------------------------
// prep: W1F frag-linear fp16 A-layout: [e(6)][kc(8)][ht(16)][lane(64)][8]
//   value = W1^T[h = ht*16 + (l&15)][d = kc*32 + (l>>4)*8 + j]
//   e 0..3 = We1, e=4 = Wa1, e=5 = Wg1
// ---------------------------------------------------------------------------
__global__ void prep_w1f(const float* __restrict__ We1, const float* __restrict__ Wa1,
                         const float* __restrict__ Wg1, _Float16* __restrict__ W1F){
  int idx = blockIdx.x * 256 + threadIdx.x;          // < 49152
  int e = idx >> 13;
  int r = idx & 8191;
  int kc = r >> 10;
  int entry = r & 1023;
  int ht = entry >> 6, ll = entry & 63;
  int h = ht * 16 + (ll & 15);
  int d0 = kc * 32 + ((ll >> 4) << 3);
  f16x8 o;
  #pragma unroll
  for (int j = 0; j < 8; ++j){
    int d = d0 + j;
    float v;
    if (e < 4)       v = We1[e * 65536 + d * 256 + h];
    else if (e == 4) v = Wa1[d * 256 + h];
    else             v = Wg1[d * 256 + h];
    o[j] = (_Float16)v;
  }
  *(f16x8*)&W1F[(size_t)idx * 8] = o;
}

// prep: W2F frag-linear fp16 A-layout: [e(6)][kc2(8)][lane(64)][8]
//   value = W2[h = kc2*32 + (l>>4)*8 + j][c = l&15], zero-padded
__global__ void prep_w2f(const float* __restrict__ We2, const float* __restrict__ Wa2,
                         const float* __restrict__ Wg2, _Float16* __restrict__ W2F){
  int idx = blockIdx.x * 256 + threadIdx.x;          // < 3072
  int e = idx >> 9;
  int r = idx & 511;
  int k2 = r >> 6, ll = r & 63;
  int c = ll & 15;
  int h0 = k2 * 32 + ((ll >> 4) << 3);
  f16x8 o;
  #pragma unroll
  for (int j = 0; j < 8; ++j){
    int h = h0 + j;
    float v = 0.0f;
    if (e < 4){ if (c < 10) v = We2[e * 2560 + h * 10 + c]; }
    else if (e == 4){ if (c < 10) v = Wa2[h * 10 + c]; }
    else { if (c < 4) v = Wg2[h * 4 + c]; }
    o[j] = (_Float16)v;
  }
  *(f16x8*)&W2F[(size_t)idx * 8] = o;
}

// ---------------------------------------------------------------------------
// fused kernel. 256 threads (4 waves), 64 tokens/block, 4096 blocks.
// wave w owns h-strip [64w,64w+64) in L1 (all 64 tokens), token-tile
// [16w,16w+16) in L2/epilogues.
// LDS: xs 32K (swizzled fp16 x) | regionB 32K (W1 dbuf <-> hs, time-disjoint)
//      | gred 4K (gate cross-wave reduce) | lsum 64B
// ---------------------------------------------------------------------------
__device__ __forceinline__ void stage_w1(const _Float16* __restrict__ W1F,
                                         int e, int kc, _Float16* __restrict__ dst,
                                         int tid){
  const f16x8* s = (const f16x8*)(W1F + (size_t)(e * 8 + kc) * 8192);
  f16x8* d = (f16x8*)dst;
  #pragma unroll
  for (int j = 0; j < 4; ++j) d[tid + j * 256] = s[tid + j * 256];
}

__global__ __launch_bounds__(256, 2) void fused_kernel(
    const float* __restrict__ x,
    const _Float16* __restrict__ W1F, const _Float16* __restrict__ W2F,
    const float* __restrict__ bg1, const float* __restrict__ Wg2,
    const float* __restrict__ bg2,
    const float* __restrict__ be1, const float* __restrict__ be2,
    const float* __restrict__ ba1, const float* __restrict__ ba2,
    float* __restrict__ out, unsigned char* __restrict__ flags,
    float* __restrict__ lpart){
  __shared__ __align__(16) unsigned char lds[69696];
  unsigned char* xsb = lds;                         // 32 KB
  _Float16*      w1b = (_Float16*)(lds + 32768);    // 2 x 16 KB (L1 phase)
  unsigned char* hsb = lds + 32768;                 // 32 KB (epilogue phase)
  float*        gred = (float*)(lds + 65536);       // 4 KB
  float*        lsum = (float*)(lds + 69632);       // 16 floats

  const int tid = threadIdx.x;
  const int w = tid >> 6, l = tid & 63;
  const int l15 = l & 15, lq = l >> 4;
  const size_t t0 = (size_t)blockIdx.x * 64;

  // ---- stage x -> fp16 swizzled LDS (coalesced 32B/lane loads) ----
  {
    int d = (tid & 31) * 8;
    #pragma unroll
    for (int q = 0; q < 8; ++q){
      int tk = q * 8 + (tid >> 5);
      const float* xp = x + (t0 + tk) * 256 + d;
      float4 f0 = *(const float4*)xp;
      float4 f1 = *(const float4*)(xp + 4);
      f16x8 h;
      h[0] = (_Float16)f0.x; h[1] = (_Float16)f0.y;
      h[2] = (_Float16)f0.z; h[3] = (_Float16)f0.w;
      h[4] = (_Float16)f1.x; h[5] = (_Float16)f1.y;
      h[6] = (_Float16)f1.z; h[7] = (_Float16)f1.w;
      *(f16x8*)(xsb + tk * 512 + ((d * 2) ^ ((tk & 7) << 4))) = h;
    }
  }

  // ================= GATE slot (W1F slot 5) =================
  f32x4 acc[4][4];
  #pragma unroll
  for (int i = 0; i < 4; ++i)
    #pragma unroll
    for (int tt = 0; tt < 4; ++tt){
      acc[i][tt][0]=0.f; acc[i][tt][1]=0.f; acc[i][tt][2]=0.f; acc[i][tt][3]=0.f;
    }
  stage_w1(W1F, 5, 0, w1b, tid);
  __syncthreads();
  for (int kc = 0; kc < 8; ++kc){
    if (kc < 7) stage_w1(W1F, 5, kc + 1, w1b + ((kc + 1) & 1) * 8192, tid);
    const _Float16* wb = w1b + (kc & 1) * 8192;
    f16x8 af[4], bf[4];
    #pragma unroll
    for (int i = 0; i < 4; ++i)
      af[i] = *(const f16x8*)&wb[((w * 4 + i) * 64 + l) * 8];
    #pragma unroll
    for (int tt = 0; tt < 4; ++tt){
      int ltok = tt * 16 + l15;
      bf[tt] = *(const f16x8*)(xsb + ltok * 512 +
                 ((kc * 64 + lq * 16) ^ ((ltok & 7) << 4)));
    }
    __builtin_amdgcn_s_setprio(1);
    #pragma unroll
    for (int i = 0; i < 4; ++i)
      #pragma unroll
      for (int tt = 0; tt < 4; ++tt)
        acc[i][tt] = mfma16(af[i], bf[tt], acc[i][tt]);
    __builtin_amdgcn_s_setprio(0);
    __syncthreads();
  }

  // gate epilogue: fp32 L2 in registers (exact erf GELU)
  float gp[4][4];
  #pragma unroll
  for (int tt = 0; tt < 4; ++tt){ gp[tt][0]=0.f; gp[tt][1]=0.f; gp[tt][2]=0.f; gp[tt][3]=0.f; }
  #pragma unroll
  for (int i = 0; i < 4; ++i){
    int hb = (w * 4 + i) * 16 + lq * 4;
    float4 b1v = *(const float4*)&bg1[hb];
    float bb[4] = {b1v.x, b1v.y, b1v.z, b1v.w};
    #pragma unroll
    for (int r = 0; r < 4; ++r){
      float4 w2 = *(const float4*)&Wg2[(hb + r) * 4];
      #pragma unroll
      for (int tt = 0; tt < 4; ++tt){
        float g = gelu_exact(acc[i][tt][r] + bb[r]);
        gp[tt][0] += g * w2.x; gp[tt][1] += g * w2.y;
        gp[tt][2] += g * w2.z; gp[tt][3] += g * w2.w;
      }
    }
  }
  #pragma unroll
  for (int tt = 0; tt < 4; ++tt)
    #pragma unroll
    for (int c = 0; c < 4; ++c){
      gp[tt][c] += __shfl_xor(gp[tt][c], 16, 64);
      gp[tt][c] += __shfl_xor(gp[tt][c], 32, 64);
    }
  if (lq == 0){
    #pragma unroll
    for (int tt = 0; tt < 4; ++tt){
      float4 v; v.x = gp[tt][0]; v.y = gp[tt][1]; v.z = gp[tt][2]; v.w = gp[tt][3];
      *(float4*)&gred[(w * 64 + tt * 16 + l15) * 4] = v;
    }
  }
  __syncthreads();
  float4 gw = {0,0,0,0};
  float4 lgw = {0,0,0,0};
  {
    int tokL = w * 16 + l15;
    if (lq == 0){
      float4 s0 = *(const float4*)&gred[(0 * 64 + tokL) * 4];
      float4 s1 = *(const float4*)&gred[(1 * 64 + tokL) * 4];
      float4 s2 = *(const float4*)&gred[(2 * 64 + tokL) * 4];
      float4 s3 = *(const float4*)&gred[(3 * 64 + tokL) * 4];
      float v0 = s0.x + s1.x + s2.x + s3.x + bg2[0];
      float v1 = s0.y + s1.y + s2.y + s3.y + bg2[1];
      float v2 = s0.z + s1.z + s2.z + s3.z + bg2[2];
      float v3 = s0.w + s1.w + s2.w + s3.w + bg2[3];
      float gap; int i1, i2;
      topk4(v0, v1, v2, v3, gw, gap, i1, i2);
      size_t t = t0 + tokL;
      *(float4*)&out[GW_OFF + t * 4] = gw;
      flags[t] = (gap < DELTA) ? (unsigned char)(1 | (i1 << 2) | (i2 << 4)) : 0;
      lgw = gw;
    }
  }
  // broadcast this token's gw to all lanes of the wave
  float4 gw4;
  gw4.x = __shfl(gw.x, l15, 64);
  gw4.y = __shfl(gw.y, l15, 64);
  gw4.z = __shfl(gw.z, l15, 64);
  gw4.w = __shfl(gw.w, l15, 64);
  // block-local load partial
  #pragma unroll
  for (int m = 1; m < 64; m <<= 1){
    lgw.x += __shfl_xor(lgw.x, m, 64); lgw.y += __shfl_xor(lgw.y, m, 64);
    lgw.z += __shfl_xor(lgw.z, m, 64); lgw.w += __shfl_xor(lgw.w, m, 64);
  }
  stage_w1(W1F, 0, 0, w1b, tid);      // prefetch expert-0 chunk 0
  if (l == 0) *(float4*)&lsum[w * 4] = lgw;
  __syncthreads();
  if (tid < 4)
    lpart[(size_t)blockIdx.x * 4 + tid] =
        lsum[tid] + lsum[4 + tid] + lsum[8 + tid] + lsum[12 + tid];

  // ================= experts 0..3 + alpha (slot 4) =================
  f32x4 lacc = {0,0,0,0};
  const int ltok = w * 16 + l15;
  const int key = (ltok & 7) << 4;
  for (int e = 0; e < 5; ++e){
    #pragma unroll
    for (int i = 0; i < 4; ++i)
      #pragma unroll
      for (int tt = 0; tt < 4; ++tt){
        acc[i][tt][0]=0.f; acc[i][tt][1]=0.f; acc[i][tt][2]=0.f; acc[i][tt][3]=0.f;
      }
    if (e > 0){ stage_w1(W1F, e, 0, w1b, tid); __syncthreads(); }
    for (int kc = 0; kc < 8; ++kc){
      if (kc < 7) stage_w1(W1F, e, kc + 1, w1b + ((kc + 1) & 1) * 8192, tid);
      const _Float16* wb = w1b + (kc & 1) * 8192;
      f16x8 af[4], bf[4];
      #pragma unroll
      for (int i = 0; i < 4; ++i)
        af[i] = *(const f16x8*)&wb[((w * 4 + i) * 64 + l) * 8];
      #pragma unroll
      for (int tt = 0; tt < 4; ++tt){
        int lt = tt * 16 + l15;
        bf[tt] = *(const f16x8*)(xsb + lt * 512 +
                   ((kc * 64 + lq * 16) ^ ((lt & 7) << 4)));
      }
      __builtin_amdgcn_s_setprio(1);
      #pragma unroll
      for (int i = 0; i < 4; ++i)
        #pragma unroll
        for (int tt = 0; tt < 4; ++tt)
          acc[i][tt] = mfma16(af[i], bf[tt], acc[i][tt]);
      __builtin_amdgcn_s_setprio(0);
      __syncthreads();
    }
    // epilogue L1: bias + fast GELU -> hs (regionB, W1 reads all done)
    const float* b1p = (e < 4) ? (be1 + e * 256) : ba1;
    #pragma unroll
    for (int i = 0; i < 4; ++i){
      int hb = (w * 4 + i) * 16 + lq * 4;
      float4 b4 = *(const float4*)&b1p[hb];
      float bb[4] = {b4.x, b4.y, b4.z, b4.w};
      #pragma unroll
      for (int tt = 0; tt < 4; ++tt){
        f16x4 hv;
        hv[0] = (_Float16)gelu_fast(acc[i][tt][0] + bb[0]);
        hv[1] = (_Float16)gelu_fast(acc[i][tt][1] + bb[1]);
        hv[2] = (_Float16)gelu_fast(acc[i][tt][2] + bb[2]);
        hv[3] = (_Float16)gelu_fast(acc[i][tt][3] + bb[3]);
        int lt = tt * 16 + l15;
        *(f16x4*)(hsb + lt * 512 + ((hb * 2) ^ ((lt & 7) << 4))) = hv;
      }
    }
    __syncthreads();
    // L2: wave w handles its 16 tokens
    f32x4 d2 = {0,0,0,0};
    #pragma unroll
    for (int k2 = 0; k2 < 8; ++k2){
      f16x8 a2 = *(const f16x8*)&W2F[((size_t)(e * 8 + k2) * 64 + l) * 8];
      f16x8 b2 = *(const f16x8*)(hsb + ltok * 512 + ((k2 * 64 + lq * 16) ^ key));
      d2 = mfma16(a2, b2, d2);
    }
    size_t t = t0 + ltok;
    if (e < 4){
      float gwv = (e == 0) ? gw4.x : (e == 1) ? gw4.y : (e == 2) ? gw4.z : gw4.w;
      #pragma unroll
      for (int r = 0; r < 4; ++r){
        int c = lq * 4 + r;
        float bv = (c < 10) ? be2[e * 10 + c] : 0.0f;
        lacc[r] += gwv * (d2[r] + bv);
      }
    } else {
      #pragma unroll
      for (int r = 0; r < 4; ++r){
        int c = lq * 4 + r;
        if (c < 10)
          out[ALPHA_OFF + t * 10 + c] = softplus_fast(d2[r] + ba2[c]) + 1e-6f;
      }
    }
    __syncthreads();   // regionB free before next slot's stage
  }
  // final logits write
  {
    size_t t = t0 + ltok;
    #pragma unroll
    for (int r = 0; r < 4; ++r){
      int c = lq * 4 + r;
      if (c < 10) out[t * 10 + c] = lacc[r];
    }
  }
}

// ---------------------------------------------------------------------------
// refine: exact fp32 gate for flagged tokens; on selection flip also
// recompute logits (all 4 experts, exact gw — non-selected have nonzero w).
// ---------------------------------------------------------------------------
__global__ __launch_bounds__(256) void refine_kernel(
    const float* __restrict__ x, const float* __restrict__ Wg1,
    const float* __restrict__ bg1, const float* __restrict__ Wg2,
    const float* __restrict__ bg2,
    const float* __restrict__ We1, const float* __restrict__ be1,
    const float* __restrict__ We2, const float* __restrict__ be2,
    const unsigned char* __restrict__ flags, float* __restrict__ out){
  int wglob = blockIdx.x * 4 + (threadIdx.x >> 6);
  int l = threadIdx.x & 63;
  int hb = l * 4;
  for (int t = wglob; t < NTOK; t += 2048){
    unsigned f = flags[t];
    if (!f) continue;
    const float* xr = x + (size_t)t * 256;
    float a0 = 0.f, a1 = 0.f, a2 = 0.f, a3 = 0.f;
    #pragma unroll 4
    for (int d = 0; d < 256; ++d){
      float xv = xr[d];
      float4 wv = *(const float4*)&Wg1[d * 256 + hb];
      a0 = fmaf(xv, wv.x, a0); a1 = fmaf(xv, wv.y, a1);
      a2 = fmaf(xv, wv.z, a2); a3 = fmaf(xv, wv.w, a3);
    }
    float4 b4 = *(const float4*)&bg1[hb];
    float g0 = gelu_exact(a0 + b4.x), g1 = gelu_exact(a1 + b4.y);
    float g2 = gelu_exact(a2 + b4.z), g3 = gelu_exact(a3 + b4.w);
    float4 w0 = *(const float4*)&Wg2[(hb + 0) * 4];
    float4 w1 = *(const float4*)&Wg2[(hb + 1) * 4];
    float4 w2 = *(const float4*)&Wg2[(hb + 2) * 4];
    float4 w3 = *(const float4*)&Wg2[(hb + 3) * 4];
    float p0 = g0 * w0.x + g1 * w1.x + g2 * w2.x + g3 * w3.x;
    float p1 = g0 * w0.y + g1 * w1.y + g2 * w2.y + g3 * w3.y;
    float p2 = g0 * w0.z + g1 * w1.z + g2 * w2.z + g3 * w3.z;
    float p3 = g0 * w0.w + g1 * w1.w + g2 * w2.w + g3 * w3.w;
    #pragma unroll
    for (int m = 1; m < 64; m <<= 1){
      p0 += __shfl_xor(p0, m, 64); p1 += __shfl_xor(p1, m, 64);
      p2 += __shfl_xor(p2, m, 64); p3 += __shfl_xor(p3, m, 64);
    }
    float4 gw; float gap; int i1, i2;
    topk4(p0 + bg2[0], p1 + bg2[1], p2 + bg2[2], p3 + bg2[3], gw, gap, i1, i2);
    if (l == 0) *(float4*)&out[GW_OFF + (size_t)t * 4] = gw;
    int oldset = (1 << ((f >> 2) & 3)) | (1 << ((f >> 4) & 3));
    int newset = (1 << i1) | (1 << i2);
    if (oldset != newset){
      // full logits recompute with exact gw (erf GELU, fp32)
      float lg[10];
      #pragma unroll
      for (int c = 0; c < 10; ++c) lg[c] = 0.f;
      for (int e = 0; e < 4; ++e){
        float gwe = (e == 0) ? gw.x : (e == 1) ? gw.y : (e == 2) ? gw.z : gw.w;
        float c0 = 0.f, c1 = 0.f, c2 = 0.f, c3 = 0.f;
        #pragma unroll 4
        for (int d = 0; d < 256; ++d){
          float xv = xr[d];
          float4 wv = *(const float4*)&We1[e * 65536 + d * 256 + hb];
          c0 = fmaf(xv, wv.x, c0); c1 = fmaf(xv, wv.y, c1);
          c2 = fmaf(xv, wv.z, c2); c3 = fmaf(xv, wv.w, c3);
        }
        float4 be = *(const float4*)&be1[e * 256 + hb];
        float h[4];
        h[0] = gelu_exact(c0 + be.x); h[1] = gelu_exact(c1 + be.y);
        h[2] = gelu_exact(c2 + be.z); h[3] = gelu_exact(c3 + be.w);
        #pragma unroll
        for (int r = 0; r < 4; ++r){
          const float* w2p = &We2[e * 2560 + (hb + r) * 10];
          #pragma unroll
          for (int c = 0; c < 10; ++c) lg[c] += gwe * (h[r] * w2p[c]);
        }
      }
      #pragma unroll
      for (int m = 1; m < 64; m <<= 1)
        #pragma unroll
        for (int c = 0; c < 10; ++c) lg[c] += __shfl_xor(lg[c], m, 64);
      if (l == 0){
        #pragma unroll
        for (int c = 0; c < 10; ++c)
          out[(size_t)t * 10 + c] = lg[c] + gw.x * be2[c] + gw.y * be2[10 + c]
                                         + gw.z * be2[20 + c] + gw.w * be2[30 + c];
      }
    }
  }
}

// deterministic tree reduce of 4096x4 partials -> load[4]
__global__ void reduce_load(const float* __restrict__ lpart, float* __restrict__ out){
  __shared__ float red[64][4];
  int tid = threadIdx.x;
  int e = tid & 3, ch = tid >> 2;
  float s = 0.0f;
  for (int i = 0; i < 64; ++i) s += lpart[(size_t)(ch * 64 + i) * 4 + e];
  red[ch][e] = s;
  __syncthreads();
  if (tid < 4){
    float t = 0.0f;
    for (int c = 0; c < 64; ++c) t += red[c][tid];
    out[LOAD_OFF + tid] = t;
  }
}

// ---------------------------------------------------------------------------
extern "C" void kernel_launch(void* const* d_in, const int* in_sizes, int n_in,
                              void* d_out, int out_size, void* d_ws, size_t ws_size,
                              hipStream_t stream){
  const float* x   = (const float*)d_in[0];
  const float* Wg1 = (const float*)d_in[1];
  const float* bg1 = (const float*)d_in[2];
  const float* Wg2 = (const float*)d_in[3];
  const float* bg2 = (const float*)d_in[4];
  const float* We1 = (const float*)d_in[5];
  const float* be1 = (const float*)d_in[6];
  const float* We2 = (const float*)d_in[7];
  const float* be2 = (const float*)d_in[8];
  const float* Wa1 = (const float*)d_in[9];
  const float* ba1 = (const float*)d_in[10];
  const float* Wa2 = (const float*)d_in[11];
  const float* ba2 = (const float*)d_in[12];
  float* out = (float*)d_out;

  _Float16* W1F        = (_Float16*)((char*)d_ws + W1F_OFF);
  _Float16* W2F        = (_Float16*)((char*)d_ws + W2F_OFF);
  unsigned char* flags = (unsigned char*)((char*)d_ws + FLAG_OFF);
  float* lpart         = (float*)((char*)d_ws + LPART_OFF);

  hipLaunchKernelGGL(prep_w1f, dim3(192), dim3(256), 0, stream, We1, Wa1, Wg1, W1F);
  hipLaunchKernelGGL(prep_w2f, dim3(12),  dim3(256), 0, stream, We2, Wa2, Wg2, W2F);
  hipLaunchKernelGGL(fused_kernel, dim3(4096), dim3(256), 0, stream,
                     x, W1F, W2F, bg1, Wg2, bg2, be1, be2, ba1, ba2,
                     out, flags, lpart);
  hipLaunchKernelGGL(refine_kernel, dim3(512), dim3(256), 0, stream,
                     x, Wg1, bg1, Wg2, bg2, We1, be1, We2, be2, flags, out);
  hipLaunchKernelGGL(reduce_load, dim3(1), dim3(256), 0, stream, lpart, out);
}

// Round 4
// 676.324 us; speedup vs baseline: 2.0027x; 1.0762x over previous
//
#include <hip/hip_runtime.h>
#include <hip/hip_bf16.h>

// ============================================================================
// ASTRAMoE v4: single fused pass, fp16 MFMA, NO LDS staging of W1.
//   W1 fragments are loaded per-kc directly from L2-resident frag-linear W1F
//   (768 KB, shared by all blocks) -> zero barriers inside every K-loop.
//   Barriers per block: ~13 (xs stage, gate reduce x2, hs reuse 2/slot).
//   gate: L1 MFMA fp16, L2 + erf-GELU in fp32 registers; flag gap<0.008,
//         exact refine afterwards. experts/alpha: L1 MFMA -> fast GELU -> hs
//         (LDS) -> L2 MFMA; gate weighting + softplus in-register.
// d_out (fp32): logits[N*10] | alpha[N*10] | gate_weights[N*4] | load[4]
// ============================================================================

typedef _Float16 f16x8 __attribute__((ext_vector_type(8)));
typedef _Float16 f16x4 __attribute__((ext_vector_type(4)));
typedef float    f32x4 __attribute__((ext_vector_type(4)));

static constexpr int    NTOK      = 262144;
static constexpr size_t ALPHA_OFF = (size_t)NTOK * 10;
static constexpr size_t GW_OFF    = (size_t)2 * NTOK * 10;
static constexpr size_t LOAD_OFF  = GW_OFF + (size_t)NTOK * 4;

// ws layout (bytes)
static constexpr size_t W1F_OFF   = 0;          // 6*65536 halfs = 786432
static constexpr size_t W2F_OFF   = 786432;     // 6*4096 halfs  = 49152
static constexpr size_t FLAG_OFF  = 835584;     // 262144 u8     = 256 KB
static constexpr size_t LPART_OFF = 1097728;    // 4096*4 f32    = 64 KB

static constexpr float DELTA = 0.008f;

__device__ __forceinline__ float gelu_exact(float v){
  return 0.5f * v * (1.0f + erff(v * 0.7071067811865475f));
}
__device__ __forceinline__ float gelu_fast(float v){
  float t = v * v;
  float p = __builtin_fmaf(0.0713548162726f, t, 1.5957691216057f);
  float z = __expf(v * p);
  float r = __builtin_amdgcn_rcpf(z + 1.0f);
  return v - v * r;
}
__device__ __forceinline__ float softplus_fast(float v){
  float z = __expf(v);
  float l = __logf(1.0f + z);
  return (v > 15.0f) ? v : l;
}
__device__ __forceinline__ f32x4 mfma16(f16x8 a, f16x8 b, f32x4 c){
  return __builtin_amdgcn_mfma_f32_16x16x32_f16(a, b, c, 0, 0, 0);
}

// exact top-2 (lowest index wins ties, matches jax.lax.top_k) + scatter-softmax
__device__ __forceinline__ void topk4(float v0, float v1, float v2, float v3,
                                      float4& gw, float& gap, int& i1, int& i2){
  float m1 = fmaxf(fmaxf(v0, v1), fmaxf(v2, v3));
  i1 = (v0 == m1) ? 0 : (v1 == m1) ? 1 : (v2 == m1) ? 2 : 3;
  float m2 = 0.f; i2 = -1;
  if (0 != i1){ m2 = v0; i2 = 0; }
  if (1 != i1 && (i2 < 0 || v1 > m2)){ m2 = v1; i2 = 1; }
  if (2 != i1 && (i2 < 0 || v2 > m2)){ m2 = v2; i2 = 2; }
  if (3 != i1 && (i2 < 0 || v3 > m2)){ m2 = v3; i2 = 3; }
  float m3 = -3.0e38f;
  if (0 != i1 && 0 != i2) m3 = fmaxf(m3, v0);
  if (1 != i1 && 1 != i2) m3 = fmaxf(m3, v1);
  if (2 != i1 && 2 != i2) m3 = fmaxf(m3, v2);
  if (3 != i1 && 3 != i2) m3 = fmaxf(m3, v3);
  gap = m2 - m3;
  float mm = fmaxf(m1, 0.0f);
  float s0 = (0 == i1 || 0 == i2) ? v0 : 0.0f;
  float s1 = (1 == i1 || 1 == i2) ? v1 : 0.0f;
  float s2 = (2 == i1 || 2 == i2) ? v2 : 0.0f;
  float s3 = (3 == i1 || 3 == i2) ? v3 : 0.0f;
  float e0 = expf(s0 - mm), e1 = expf(s1 - mm), e2 = expf(s2 - mm), e3 = expf(s3 - mm);
  float inv = 1.0f / (e0 + e1 + e2 + e3);
  gw.x = e0 * inv; gw.y = e1 * inv; gw.z = e2 * inv; gw.w = e3 * inv;
}

// ---------------------------------------------------------------------------
// prep: W1F frag-linear fp16 A-layout: [e(6)][kc(8)][ht(16)][lane(64)][8]
//   value = W1^T[h = ht*16 + (l&15)][d = kc*32 + (l>>4)*8 + j]
//   e 0..3 = We1, e=4 = Wa1, e=5 = Wg1
// ---------------------------------------------------------------------------
__global__ void prep_w1f(const float* __restrict__ We1, const float* __restrict__ Wa1,
                         const float* __restrict__ Wg1, _Float16* __restrict__ W1F){
  int idx = blockIdx.x * 256 + threadIdx.x;          // < 49152
  int e = idx >> 13;
  int r = idx & 8191;
  int kc = r >> 10;
  int entry = r & 1023;
  int ht = entry >> 6, ll = entry & 63;
  int h = ht * 16 + (ll & 15);
  int d0 = kc * 32 + ((ll >> 4) << 3);
  f16x8 o;
  #pragma unroll
  for (int j = 0; j < 8; ++j){
    int d = d0 + j;
    float v;
    if (e < 4)       v = We1[e * 65536 + d * 256 + h];
    else if (e == 4) v = Wa1[d * 256 + h];
    else             v = Wg1[d * 256 + h];
    o[j] = (_Float16)v;
  }
  *(f16x8*)&W1F[(size_t)idx * 8] = o;
}

// prep: W2F frag-linear fp16 A-layout: [e(6)][kc2(8)][lane(64)][8]
//   value = W2[h = kc2*32 + (l>>4)*8 + j][c = l&15], zero-padded
__global__ void prep_w2f(const float* __restrict__ We2, const float* __restrict__ Wa2,
                         const float* __restrict__ Wg2, _Float16* __restrict__ W2F){
  int idx = blockIdx.x * 256 + threadIdx.x;          // < 3072
  int e = idx >> 9;
  int r = idx & 511;
  int k2 = r >> 6, ll = r & 63;
  int c = ll & 15;
  int h0 = k2 * 32 + ((ll >> 4) << 3);
  f16x8 o;
  #pragma unroll
  for (int j = 0; j < 8; ++j){
    int h = h0 + j;
    float v = 0.0f;
    if (e < 4){ if (c < 10) v = We2[e * 2560 + h * 10 + c]; }
    else if (e == 4){ if (c < 10) v = Wa2[h * 10 + c]; }
    else { if (c < 4) v = Wg2[h * 4 + c]; }
    o[j] = (_Float16)v;
  }
  *(f16x8*)&W2F[(size_t)idx * 8] = o;
}

// ---------------------------------------------------------------------------
// fused kernel. 256 threads (4 waves), 64 tokens/block, 4096 blocks.
// wave w owns h-strip [64w,64w+64) in L1 (all 64 tokens), token-tile
// [16w,16w+16) in L2/epilogues.
// LDS: xs 32K (swizzled fp16 x) | hs 32K | gred 4K | lsum 64B  = 68.1 KB
//   -> 2 blocks/CU. No W1 in LDS: A-frags stream from L2 each kc-step.
// ---------------------------------------------------------------------------
// L1 inner loop: 8 kc-steps, barrier-free. A-frags from global (L2-hit),
// B-frags from xs. Fully unrolled so the compiler software-pipelines loads.
__device__ __forceinline__ void run_l1(const _Float16* __restrict__ w1s,
                                       const unsigned char* __restrict__ xsb,
                                       int w, int l, int l15, int lq,
                                       f32x4 acc[4][4]){
  #pragma unroll
  for (int kc = 0; kc < 8; ++kc){
    f16x8 af[4], bf[4];
    #pragma unroll
    for (int i = 0; i < 4; ++i)
      af[i] = *(const f16x8*)&w1s[(size_t)kc * 8192 + (w * 4 + i) * 512 + l * 8];
    #pragma unroll
    for (int tt = 0; tt < 4; ++tt){
      int lt = tt * 16 + l15;
      bf[tt] = *(const f16x8*)(xsb + lt * 512 +
                 ((kc * 64 + lq * 16) ^ ((lt & 7) << 4)));
    }
    __builtin_amdgcn_s_setprio(1);
    #pragma unroll
    for (int i = 0; i < 4; ++i)
      #pragma unroll
      for (int tt = 0; tt < 4; ++tt)
        acc[i][tt] = mfma16(af[i], bf[tt], acc[i][tt]);
    __builtin_amdgcn_s_setprio(0);
  }
}

__global__ __launch_bounds__(256, 2) void fused_kernel(
    const float* __restrict__ x,
    const _Float16* __restrict__ W1F, const _Float16* __restrict__ W2F,
    const float* __restrict__ bg1, const float* __restrict__ Wg2,
    const float* __restrict__ bg2,
    const float* __restrict__ be1, const float* __restrict__ be2,
    const float* __restrict__ ba1, const float* __restrict__ ba2,
    float* __restrict__ out, unsigned char* __restrict__ flags,
    float* __restrict__ lpart){
  __shared__ __align__(16) unsigned char lds[69696];
  unsigned char* xsb = lds;                         // 32 KB
  unsigned char* hsb = lds + 32768;                 // 32 KB
  float*        gred = (float*)(lds + 65536);       // 4 KB
  float*        lsum = (float*)(lds + 69632);       // 16 floats

  const int tid = threadIdx.x;
  const int w = tid >> 6, l = tid & 63;
  const int l15 = l & 15, lq = l >> 4;
  const size_t t0 = (size_t)blockIdx.x * 64;

  // ---- stage x -> fp16 swizzled LDS (coalesced 32B/lane loads) ----
  {
    int d = (tid & 31) * 8;
    #pragma unroll
    for (int q = 0; q < 8; ++q){
      int tk = q * 8 + (tid >> 5);
      const float* xp = x + (t0 + tk) * 256 + d;
      float4 f0 = *(const float4*)xp;
      float4 f1 = *(const float4*)(xp + 4);
      f16x8 h;
      h[0] = (_Float16)f0.x; h[1] = (_Float16)f0.y;
      h[2] = (_Float16)f0.z; h[3] = (_Float16)f0.w;
      h[4] = (_Float16)f1.x; h[5] = (_Float16)f1.y;
      h[6] = (_Float16)f1.z; h[7] = (_Float16)f1.w;
      *(f16x8*)(xsb + tk * 512 + ((d * 2) ^ ((tk & 7) << 4))) = h;
    }
  }
  __syncthreads();

  // ================= GATE slot (W1F slot 5) =================
  f32x4 acc[4][4];
  #pragma unroll
  for (int i = 0; i < 4; ++i)
    #pragma unroll
    for (int tt = 0; tt < 4; ++tt){
      acc[i][tt][0]=0.f; acc[i][tt][1]=0.f; acc[i][tt][2]=0.f; acc[i][tt][3]=0.f;
    }
  run_l1(W1F + (size_t)5 * 65536, xsb, w, l, l15, lq, acc);

  // gate epilogue: fp32 L2 in registers (exact erf GELU)
  float gp[4][4];
  #pragma unroll
  for (int tt = 0; tt < 4; ++tt){ gp[tt][0]=0.f; gp[tt][1]=0.f; gp[tt][2]=0.f; gp[tt][3]=0.f; }
  #pragma unroll
  for (int i = 0; i < 4; ++i){
    int hb = (w * 4 + i) * 16 + lq * 4;
    float4 b1v = *(const float4*)&bg1[hb];
    float bb[4] = {b1v.x, b1v.y, b1v.z, b1v.w};
    #pragma unroll
    for (int r = 0; r < 4; ++r){
      float4 w2 = *(const float4*)&Wg2[(hb + r) * 4];
      #pragma unroll
      for (int tt = 0; tt < 4; ++tt){
        float g = gelu_exact(acc[i][tt][r] + bb[r]);
        gp[tt][0] += g * w2.x; gp[tt][1] += g * w2.y;
        gp[tt][2] += g * w2.z; gp[tt][3] += g * w2.w;
      }
    }
  }
  #pragma unroll
  for (int tt = 0; tt < 4; ++tt)
    #pragma unroll
    for (int c = 0; c < 4; ++c){
      gp[tt][c] += __shfl_xor(gp[tt][c], 16, 64);
      gp[tt][c] += __shfl_xor(gp[tt][c], 32, 64);
    }
  if (lq == 0){
    #pragma unroll
    for (int tt = 0; tt < 4; ++tt){
      float4 v; v.x = gp[tt][0]; v.y = gp[tt][1]; v.z = gp[tt][2]; v.w = gp[tt][3];
      *(float4*)&gred[(w * 64 + tt * 16 + l15) * 4] = v;
    }
  }
  __syncthreads();
  float4 gw = {0,0,0,0};
  float4 lgw = {0,0,0,0};
  {
    int tokL = w * 16 + l15;
    if (lq == 0){
      float4 s0 = *(const float4*)&gred[(0 * 64 + tokL) * 4];
      float4 s1 = *(const float4*)&gred[(1 * 64 + tokL) * 4];
      float4 s2 = *(const float4*)&gred[(2 * 64 + tokL) * 4];
      float4 s3 = *(const float4*)&gred[(3 * 64 + tokL) * 4];
      float v0 = s0.x + s1.x + s2.x + s3.x + bg2[0];
      float v1 = s0.y + s1.y + s2.y + s3.y + bg2[1];
      float v2 = s0.z + s1.z + s2.z + s3.z + bg2[2];
      float v3 = s0.w + s1.w + s2.w + s3.w + bg2[3];
      float gap; int i1, i2;
      topk4(v0, v1, v2, v3, gw, gap, i1, i2);
      size_t t = t0 + tokL;
      *(float4*)&out[GW_OFF + t * 4] = gw;
      flags[t] = (gap < DELTA) ? (unsigned char)(1 | (i1 << 2) | (i2 << 4)) : 0;
      lgw = gw;
    }
  }
  // broadcast this token's gw to all lanes of the wave
  float4 gw4;
  gw4.x = __shfl(gw.x, l15, 64);
  gw4.y = __shfl(gw.y, l15, 64);
  gw4.z = __shfl(gw.z, l15, 64);
  gw4.w = __shfl(gw.w, l15, 64);
  // block-local load partial
  #pragma unroll
  for (int m = 1; m < 64; m <<= 1){
    lgw.x += __shfl_xor(lgw.x, m, 64); lgw.y += __shfl_xor(lgw.y, m, 64);
    lgw.z += __shfl_xor(lgw.z, m, 64); lgw.w += __shfl_xor(lgw.w, m, 64);
  }
  if (l == 0) *(float4*)&lsum[w * 4] = lgw;
  __syncthreads();
  if (tid < 4)
    lpart[(size_t)blockIdx.x * 4 + tid] =
        lsum[tid] + lsum[4 + tid] + lsum[8 + tid] + lsum[12 + tid];

  // ================= experts 0..3 + alpha (slot 4) =================
  f32x4 lacc = {0,0,0,0};
  const int ltok = w * 16 + l15;
  const int key = (ltok & 7) << 4;
  for (int e = 0; e < 5; ++e){
    #pragma unroll
    for (int i = 0; i < 4; ++i)
      #pragma unroll
      for (int tt = 0; tt < 4; ++tt){
        acc[i][tt][0]=0.f; acc[i][tt][1]=0.f; acc[i][tt][2]=0.f; acc[i][tt][3]=0.f;
      }
    run_l1(W1F + (size_t)e * 65536, xsb, w, l, l15, lq, acc);

    // epilogue L1: bias + fast GELU -> hs (all hs[e-1] readers are done:
    // the post-L2 barrier of slot e-1 precedes this)
    const float* b1p = (e < 4) ? (be1 + e * 256) : ba1;
    #pragma unroll
    for (int i = 0; i < 4; ++i){
      int hb = (w * 4 + i) * 16 + lq * 4;
      float4 b4 = *(const float4*)&b1p[hb];
      float bb[4] = {b4.x, b4.y, b4.z, b4.w};
      #pragma unroll
      for (int tt = 0; tt < 4; ++tt){
        f16x4 hv;
        hv[0] = (_Float16)gelu_fast(acc[i][tt][0] + bb[0]);
        hv[1] = (_Float16)gelu_fast(acc[i][tt][1] + bb[1]);
        hv[2] = (_Float16)gelu_fast(acc[i][tt][2] + bb[2]);
        hv[3] = (_Float16)gelu_fast(acc[i][tt][3] + bb[3]);
        int lt = tt * 16 + l15;
        *(f16x4*)(hsb + lt * 512 + ((hb * 2) ^ ((lt & 7) << 4))) = hv;
      }
    }
    __syncthreads();
    // L2: wave w handles its 16 tokens
    f32x4 d2 = {0,0,0,0};
    #pragma unroll
    for (int k2 = 0; k2 < 8; ++k2){
      f16x8 a2 = *(const f16x8*)&W2F[((size_t)(e * 8 + k2) * 64 + l) * 8];
      f16x8 b2 = *(const f16x8*)(hsb + ltok * 512 + ((k2 * 64 + lq * 16) ^ key));
      d2 = mfma16(a2, b2, d2);
    }
    size_t t = t0 + ltok;
    if (e < 4){
      float gwv = (e == 0) ? gw4.x : (e == 1) ? gw4.y : (e == 2) ? gw4.z : gw4.w;
      #pragma unroll
      for (int r = 0; r < 4; ++r){
        int c = lq * 4 + r;
        float bv = (c < 10) ? be2[e * 10 + c] : 0.0f;
        lacc[r] += gwv * (d2[r] + bv);
      }
    } else {
      #pragma unroll
      for (int r = 0; r < 4; ++r){
        int c = lq * 4 + r;
        if (c < 10)
          out[ALPHA_OFF + t * 10 + c] = softplus_fast(d2[r] + ba2[c]) + 1e-6f;
      }
    }
    if (e < 4) __syncthreads();   // hs free before next slot's writes
  }
  // final logits write
  {
    size_t t = t0 + ltok;
    #pragma unroll
    for (int r = 0; r < 4; ++r){
      int c = lq * 4 + r;
      if (c < 10) out[t * 10 + c] = lacc[r];
    }
  }
}

// ---------------------------------------------------------------------------
// refine: exact fp32 gate for flagged tokens; on selection flip also
// recompute logits (all 4 experts, exact gw — non-selected have nonzero w).
// ---------------------------------------------------------------------------
__global__ __launch_bounds__(256) void refine_kernel(
    const float* __restrict__ x, const float* __restrict__ Wg1,
    const float* __restrict__ bg1, const float* __restrict__ Wg2,
    const float* __restrict__ bg2,
    const float* __restrict__ We1, const float* __restrict__ be1,
    const float* __restrict__ We2, const float* __restrict__ be2,
    const unsigned char* __restrict__ flags, float* __restrict__ out){
  int wglob = blockIdx.x * 4 + (threadIdx.x >> 6);
  int l = threadIdx.x & 63;
  int hb = l * 4;
  for (int t = wglob; t < NTOK; t += 2048){
    unsigned f = flags[t];
    if (!f) continue;
    const float* xr = x + (size_t)t * 256;
    float a0 = 0.f, a1 = 0.f, a2 = 0.f, a3 = 0.f;
    #pragma unroll 4
    for (int d = 0; d < 256; ++d){
      float xv = xr[d];
      float4 wv = *(const float4*)&Wg1[d * 256 + hb];
      a0 = fmaf(xv, wv.x, a0); a1 = fmaf(xv, wv.y, a1);
      a2 = fmaf(xv, wv.z, a2); a3 = fmaf(xv, wv.w, a3);
    }
    float4 b4 = *(const float4*)&bg1[hb];
    float g0 = gelu_exact(a0 + b4.x), g1 = gelu_exact(a1 + b4.y);
    float g2 = gelu_exact(a2 + b4.z), g3 = gelu_exact(a3 + b4.w);
    float4 w0 = *(const float4*)&Wg2[(hb + 0) * 4];
    float4 w1 = *(const float4*)&Wg2[(hb + 1) * 4];
    float4 w2 = *(const float4*)&Wg2[(hb + 2) * 4];
    float4 w3 = *(const float4*)&Wg2[(hb + 3) * 4];
    float p0 = g0 * w0.x + g1 * w1.x + g2 * w2.x + g3 * w3.x;
    float p1 = g0 * w0.y + g1 * w1.y + g2 * w2.y + g3 * w3.y;
    float p2 = g0 * w0.z + g1 * w1.z + g2 * w2.z + g3 * w3.z;
    float p3 = g0 * w0.w + g1 * w1.w + g2 * w2.w + g3 * w3.w;
    #pragma unroll
    for (int m = 1; m < 64; m <<= 1){
      p0 += __shfl_xor(p0, m, 64); p1 += __shfl_xor(p1, m, 64);
      p2 += __shfl_xor(p2, m, 64); p3 += __shfl_xor(p3, m, 64);
    }
    float4 gw; float gap; int i1, i2;
    topk4(p0 + bg2[0], p1 + bg2[1], p2 + bg2[2], p3 + bg2[3], gw, gap, i1, i2);
    if (l == 0) *(float4*)&out[GW_OFF + (size_t)t * 4] = gw;
    int oldset = (1 << ((f >> 2) & 3)) | (1 << ((f >> 4) & 3));
    int newset = (1 << i1) | (1 << i2);
    if (oldset != newset){
      // full logits recompute with exact gw (erf GELU, fp32)
      float lg[10];
      #pragma unroll
      for (int c = 0; c < 10; ++c) lg[c] = 0.f;
      for (int e = 0; e < 4; ++e){
        float gwe = (e == 0) ? gw.x : (e == 1) ? gw.y : (e == 2) ? gw.z : gw.w;
        float c0 = 0.f, c1 = 0.f, c2 = 0.f, c3 = 0.f;
        #pragma unroll 4
        for (int d = 0; d < 256; ++d){
          float xv = xr[d];
          float4 wv = *(const float4*)&We1[e * 65536 + d * 256 + hb];
          c0 = fmaf(xv, wv.x, c0); c1 = fmaf(xv, wv.y, c1);
          c2 = fmaf(xv, wv.z, c2); c3 = fmaf(xv, wv.w, c3);
        }
        float4 be = *(const float4*)&be1[e * 256 + hb];
        float h[4];
        h[0] = gelu_exact(c0 + be.x); h[1] = gelu_exact(c1 + be.y);
        h[2] = gelu_exact(c2 + be.z); h[3] = gelu_exact(c3 + be.w);
        #pragma unroll
        for (int r = 0; r < 4; ++r){
          const float* w2p = &We2[e * 2560 + (hb + r) * 10];
          #pragma unroll
          for (int c = 0; c < 10; ++c) lg[c] += gwe * (h[r] * w2p[c]);
        }
      }
      #pragma unroll
      for (int m = 1; m < 64; m <<= 1)
        #pragma unroll
        for (int c = 0; c < 10; ++c) lg[c] += __shfl_xor(lg[c], m, 64);
      if (l == 0){
        #pragma unroll
        for (int c = 0; c < 10; ++c)
          out[(size_t)t * 10 + c] = lg[c] + gw.x * be2[c] + gw.y * be2[10 + c]
                                         + gw.z * be2[20 + c] + gw.w * be2[30 + c];
      }
    }
  }
}

// deterministic tree reduce of 4096x4 partials -> load[4]
__global__ void reduce_load(const float* __restrict__ lpart, float* __restrict__ out){
  __shared__ float red[64][4];
  int tid = threadIdx.x;
  int e = tid & 3, ch = tid >> 2;
  float s = 0.0f;
  for (int i = 0; i < 64; ++i) s += lpart[(size_t)(ch * 64 + i) * 4 + e];
  red[ch][e] = s;
  __syncthreads();
  if (tid < 4){
    float t = 0.0f;
    for (int c = 0; c < 64; ++c) t += red[c][tid];
    out[LOAD_OFF + tid] = t;
  }
}

// ---------------------------------------------------------------------------
extern "C" void kernel_launch(void* const* d_in, const int* in_sizes, int n_in,
                              void* d_out, int out_size, void* d_ws, size_t ws_size,
                              hipStream_t stream){
  const float* x   = (const float*)d_in[0];
  const float* Wg1 = (const float*)d_in[1];
  const float* bg1 = (const float*)d_in[2];
  const float* Wg2 = (const float*)d_in[3];
  const float* bg2 = (const float*)d_in[4];
  const float* We1 = (const float*)d_in[5];
  const float* be1 = (const float*)d_in[6];
  const float* We2 = (const float*)d_in[7];
  const float* be2 = (const float*)d_in[8];
  const float* Wa1 = (const float*)d_in[9];
  const float* ba1 = (const float*)d_in[10];
  const float* Wa2 = (const float*)d_in[11];
  const float* ba2 = (const float*)d_in[12];
  float* out = (float*)d_out;

  _Float16* W1F        = (_Float16*)((char*)d_ws + W1F_OFF);
  _Float16* W2F        = (_Float16*)((char*)d_ws + W2F_OFF);
  unsigned char* flags = (unsigned char*)((char*)d_ws + FLAG_OFF);
  float* lpart         = (float*)((char*)d_ws + LPART_OFF);

  hipLaunchKernelGGL(prep_w1f, dim3(192), dim3(256), 0, stream, We1, Wa1, Wg1, W1F);
  hipLaunchKernelGGL(prep_w2f, dim3(12),  dim3(256), 0, stream, We2, Wa2, Wg2, W2F);
  hipLaunchKernelGGL(fused_kernel, dim3(4096), dim3(256), 0, stream,
                     x, W1F, W2F, bg1, Wg2, bg2, be1, be2, ba1, ba2,
                     out, flags, lpart);
  hipLaunchKernelGGL(refine_kernel, dim3(512), dim3(256), 0, stream,
                     x, Wg1, bg1, Wg2, bg2, We1, be1, We2, be2, flags, out);
  hipLaunchKernelGGL(reduce_load, dim3(1), dim3(256), 0, stream, lpart, out);
}

// Round 5
// 668.465 us; speedup vs baseline: 2.0262x; 1.0118x over previous
//
#include <hip/hip_runtime.h>
#include <hip/hip_bf16.h>

// ============================================================================
// ASTRAMoE v5: fused pass (gate + 4 experts + alpha), fp16 MFMA.
//   - 3 blocks/CU: LDS 49.2 KB (hs halved to [64][128], L2 split in 2 k-phases)
//   - gate epilogue: gelu_fast (no erf in hot kernel), DELTA=0.025
//   - packed cvt_pkrtz conversions; compacted refine list (ballot+atomic)
// d_out (fp32): logits[N*10] | alpha[N*10] | gate_weights[N*4] | load[4]
// ============================================================================

typedef _Float16 f16x8 __attribute__((ext_vector_type(8)));
typedef _Float16 f16x4 __attribute__((ext_vector_type(4)));
typedef _Float16 f16x2 __attribute__((ext_vector_type(2)));
typedef float    f32x4 __attribute__((ext_vector_type(4)));

static constexpr int    NTOK      = 262144;
static constexpr size_t ALPHA_OFF = (size_t)NTOK * 10;
static constexpr size_t GW_OFF    = (size_t)2 * NTOK * 10;
static constexpr size_t LOAD_OFF  = GW_OFF + (size_t)NTOK * 4;

// ws layout (bytes)
static constexpr size_t W1F_OFF   = 0;          // 6*65536 halfs = 786432
static constexpr size_t W2F_OFF   = 786432;     // 6*4096 halfs  = 49152
static constexpr size_t CNT_OFF   = 835584;     // u32 counter (64 B slot)
static constexpr size_t LIST_OFF  = 835648;     // 262144 u32   = 1 MB
static constexpr size_t LPART_OFF = 1884224;    // 4096*4 f32   = 64 KB

static constexpr float DELTA = 0.025f;

__device__ __forceinline__ float gelu_exact(float v){
  return 0.5f * v * (1.0f + erff(v * 0.7071067811865475f));
}
__device__ __forceinline__ float gelu_fast(float v){
  float t = v * v;
  float p = __builtin_fmaf(0.0713548162726f, t, 1.5957691216057f);
  float z = __expf(v * p);
  float r = __builtin_amdgcn_rcpf(z + 1.0f);
  return v - v * r;
}
__device__ __forceinline__ float softplus_fast(float v){
  float z = __expf(v);
  float l = __logf(1.0f + z);
  return (v > 15.0f) ? v : l;
}
__device__ __forceinline__ f32x4 mfma16(f16x8 a, f16x8 b, f32x4 c){
  return __builtin_amdgcn_mfma_f32_16x16x32_f16(a, b, c, 0, 0, 0);
}
__device__ __forceinline__ f16x8 pk8(float4 a, float4 b){
  union { f16x8 v; unsigned u[4]; } r;
  r.u[0] = __builtin_bit_cast(unsigned, __builtin_amdgcn_cvt_pkrtz(a.x, a.y));
  r.u[1] = __builtin_bit_cast(unsigned, __builtin_amdgcn_cvt_pkrtz(a.z, a.w));
  r.u[2] = __builtin_bit_cast(unsigned, __builtin_amdgcn_cvt_pkrtz(b.x, b.y));
  r.u[3] = __builtin_bit_cast(unsigned, __builtin_amdgcn_cvt_pkrtz(b.z, b.w));
  return r.v;
}
__device__ __forceinline__ f16x4 pk4(float a, float b, float c, float d){
  union { f16x4 v; unsigned u[2]; } r;
  r.u[0] = __builtin_bit_cast(unsigned, __builtin_amdgcn_cvt_pkrtz(a, b));
  r.u[1] = __builtin_bit_cast(unsigned, __builtin_amdgcn_cvt_pkrtz(c, d));
  return r.v;
}

// exact top-2 (lowest index wins ties, matches jax.lax.top_k) + scatter-softmax
__device__ __forceinline__ void topk4(float v0, float v1, float v2, float v3,
                                      float4& gw, float& gap, int& i1, int& i2){
  float m1 = fmaxf(fmaxf(v0, v1), fmaxf(v2, v3));
  i1 = (v0 == m1) ? 0 : (v1 == m1) ? 1 : (v2 == m1) ? 2 : 3;
  float m2 = 0.f; i2 = -1;
  if (0 != i1){ m2 = v0; i2 = 0; }
  if (1 != i1 && (i2 < 0 || v1 > m2)){ m2 = v1; i2 = 1; }
  if (2 != i1 && (i2 < 0 || v2 > m2)){ m2 = v2; i2 = 2; }
  if (3 != i1 && (i2 < 0 || v3 > m2)){ m2 = v3; i2 = 3; }
  float m3 = -3.0e38f;
  if (0 != i1 && 0 != i2) m3 = fmaxf(m3, v0);
  if (1 != i1 && 1 != i2) m3 = fmaxf(m3, v1);
  if (2 != i1 && 2 != i2) m3 = fmaxf(m3, v2);
  if (3 != i1 && 3 != i2) m3 = fmaxf(m3, v3);
  gap = m2 - m3;
  float mm = fmaxf(m1, 0.0f);
  float s0 = (0 == i1 || 0 == i2) ? v0 : 0.0f;
  float s1 = (1 == i1 || 1 == i2) ? v1 : 0.0f;
  float s2 = (2 == i1 || 2 == i2) ? v2 : 0.0f;
  float s3 = (3 == i1 || 3 == i2) ? v3 : 0.0f;
  float e0 = expf(s0 - mm), e1 = expf(s1 - mm), e2 = expf(s2 - mm), e3 = expf(s3 - mm);
  float inv = 1.0f / (e0 + e1 + e2 + e3);
  gw.x = e0 * inv; gw.y = e1 * inv; gw.z = e2 * inv; gw.w = e3 * inv;
}

// ---------------------------------------------------------------------------
// prep: W1F frag-linear fp16 A-layout: [e(6)][kc(8)][ht(16)][lane(64)][8]
//   value = W1^T[h = ht*16 + (l&15)][d = kc*32 + (l>>4)*8 + j]
// ---------------------------------------------------------------------------
__global__ void prep_w1f(const float* __restrict__ We1, const float* __restrict__ Wa1,
                         const float* __restrict__ Wg1, _Float16* __restrict__ W1F){
  int idx = blockIdx.x * 256 + threadIdx.x;          // < 49152
  int e = idx >> 13;
  int r = idx & 8191;
  int kc = r >> 10;
  int entry = r & 1023;
  int ht = entry >> 6, ll = entry & 63;
  int h = ht * 16 + (ll & 15);
  int d0 = kc * 32 + ((ll >> 4) << 3);
  f16x8 o;
  #pragma unroll
  for (int j = 0; j < 8; ++j){
    int d = d0 + j;
    float v;
    if (e < 4)       v = We1[e * 65536 + d * 256 + h];
    else if (e == 4) v = Wa1[d * 256 + h];
    else             v = Wg1[d * 256 + h];
    o[j] = (_Float16)v;
  }
  *(f16x8*)&W1F[(size_t)idx * 8] = o;
}

// prep: W2F frag-linear fp16 A-layout: [e(6)][kc2(8)][lane(64)][8]; zero counter
__global__ void prep_w2f(const float* __restrict__ We2, const float* __restrict__ Wa2,
                         const float* __restrict__ Wg2, _Float16* __restrict__ W2F,
                         unsigned int* __restrict__ cntp){
  if (blockIdx.x == 0 && threadIdx.x == 0) *cntp = 0;
  int idx = blockIdx.x * 256 + threadIdx.x;          // < 3072
  int e = idx >> 9;
  int r = idx & 511;
  int k2 = r >> 6, ll = r & 63;
  int c = ll & 15;
  int h0 = k2 * 32 + ((ll >> 4) << 3);
  f16x8 o;
  #pragma unroll
  for (int j = 0; j < 8; ++j){
    int h = h0 + j;
    float v = 0.0f;
    if (e < 4){ if (c < 10) v = We2[e * 2560 + h * 10 + c]; }
    else if (e == 4){ if (c < 10) v = Wa2[h * 10 + c]; }
    else { if (c < 4) v = Wg2[h * 4 + c]; }
    o[j] = (_Float16)v;
  }
  *(f16x8*)&W2F[(size_t)idx * 8] = o;
}

// ---------------------------------------------------------------------------
// fused kernel. 256 threads (4 waves), 64 tokens/block, 4096 blocks.
// Wave w owns interleaved h-tiles {w, w+4, w+8, w+12} in L1 (i = tile index
// /4), token-tile [16w,16w+16) in L2/epilogues. L2 done in 2 k-phases over a
// half-size hs, so LDS = xs 32K + hs 16K (gred overlaid) + lsum = 49.2 KB
// -> 3 blocks/CU.
// ---------------------------------------------------------------------------
__device__ __forceinline__ void run_l1(const _Float16* __restrict__ w1s,
                                       const unsigned char* __restrict__ xsb,
                                       int w, int l, int l15, int lq,
                                       f32x4 acc[4][4]){
  #pragma unroll
  for (int kc = 0; kc < 8; ++kc){
    f16x8 af[4], bf[4];
    #pragma unroll
    for (int i = 0; i < 4; ++i)
      af[i] = *(const f16x8*)&w1s[(size_t)kc * 8192 + (w + 4 * i) * 512 + l * 8];
    #pragma unroll
    for (int tt = 0; tt < 4; ++tt){
      int lt = tt * 16 + l15;
      bf[tt] = *(const f16x8*)(xsb + lt * 512 +
                 ((kc * 64 + lq * 16) ^ ((lt & 7) << 4)));
    }
    __builtin_amdgcn_s_setprio(1);
    #pragma unroll
    for (int i = 0; i < 4; ++i)
      #pragma unroll
      for (int tt = 0; tt < 4; ++tt)
        acc[i][tt] = mfma16(af[i], bf[tt], acc[i][tt]);
    __builtin_amdgcn_s_setprio(0);
  }
}

__global__ __launch_bounds__(256, 4) void fused_kernel(
    const float* __restrict__ x,
    const _Float16* __restrict__ W1F, const _Float16* __restrict__ W2F,
    const float* __restrict__ bg1, const float* __restrict__ Wg2,
    const float* __restrict__ bg2,
    const float* __restrict__ be1, const float* __restrict__ be2,
    const float* __restrict__ ba1, const float* __restrict__ ba2,
    float* __restrict__ out, unsigned int* __restrict__ list,
    unsigned int* __restrict__ cntp, float* __restrict__ lpart){
  __shared__ __align__(16) unsigned char lds[49216];
  unsigned char* xsb = lds;                         // 32 KB
  unsigned char* hsb = lds + 32768;                 // 16 KB ([64 tok][128 h])
  float*        gred = (float*)(lds + 32768);       // 4 KB overlay (gate only)
  float*        lsum = (float*)(lds + 49152);       // 16 floats

  const int tid = threadIdx.x;
  const int w = tid >> 6, l = tid & 63;
  const int l15 = l & 15, lq = l >> 4;
  const size_t t0 = (size_t)blockIdx.x * 64;

  // ---- stage x -> fp16 swizzled LDS (coalesced 32B/lane loads) ----
  {
    int d = (tid & 31) * 8;
    #pragma unroll
    for (int q = 0; q < 8; ++q){
      int tk = q * 8 + (tid >> 5);
      const float* xp = x + (t0 + tk) * 256 + d;
      float4 f0 = *(const float4*)xp;
      float4 f1 = *(const float4*)(xp + 4);
      *(f16x8*)(xsb + tk * 512 + ((d * 2) ^ ((tk & 7) << 4))) = pk8(f0, f1);
    }
  }
  __syncthreads();

  // ================= GATE slot (W1F slot 5) =================
  f32x4 acc[4][4];
  #pragma unroll
  for (int i = 0; i < 4; ++i)
    #pragma unroll
    for (int tt = 0; tt < 4; ++tt){
      acc[i][tt][0]=0.f; acc[i][tt][1]=0.f; acc[i][tt][2]=0.f; acc[i][tt][3]=0.f;
    }
  run_l1(W1F + (size_t)5 * 65536, xsb, w, l, l15, lq, acc);

  // gate epilogue: fp32 L2 in registers (fast GELU; refine fixes near-ties)
  float gp[4][4];
  #pragma unroll
  for (int tt = 0; tt < 4; ++tt){ gp[tt][0]=0.f; gp[tt][1]=0.f; gp[tt][2]=0.f; gp[tt][3]=0.f; }
  #pragma unroll
  for (int i = 0; i < 4; ++i){
    int hb = (w + 4 * i) * 16 + lq * 4;
    float4 b1v = *(const float4*)&bg1[hb];
    float bb[4] = {b1v.x, b1v.y, b1v.z, b1v.w};
    #pragma unroll
    for (int r = 0; r < 4; ++r){
      float4 w2 = *(const float4*)&Wg2[(hb + r) * 4];
      #pragma unroll
      for (int tt = 0; tt < 4; ++tt){
        float g = gelu_fast(acc[i][tt][r] + bb[r]);
        gp[tt][0] += g * w2.x; gp[tt][1] += g * w2.y;
        gp[tt][2] += g * w2.z; gp[tt][3] += g * w2.w;
      }
    }
  }
  #pragma unroll
  for (int tt = 0; tt < 4; ++tt)
    #pragma unroll
    for (int c = 0; c < 4; ++c){
      gp[tt][c] += __shfl_xor(gp[tt][c], 16, 64);
      gp[tt][c] += __shfl_xor(gp[tt][c], 32, 64);
    }
  if (lq == 0){
    #pragma unroll
    for (int tt = 0; tt < 4; ++tt){
      float4 v; v.x = gp[tt][0]; v.y = gp[tt][1]; v.z = gp[tt][2]; v.w = gp[tt][3];
      *(float4*)&gred[(w * 64 + tt * 16 + l15) * 4] = v;
    }
  }
  __syncthreads();
  float4 gw = {0,0,0,0};
  float4 lgw = {0,0,0,0};
  int i1 = 0, i2 = 0;
  bool flagged = false;
  const int tokL = w * 16 + l15;
  if (lq == 0){
    float4 s0 = *(const float4*)&gred[(0 * 64 + tokL) * 4];
    float4 s1 = *(const float4*)&gred[(1 * 64 + tokL) * 4];
    float4 s2 = *(const float4*)&gred[(2 * 64 + tokL) * 4];
    float4 s3 = *(const float4*)&gred[(3 * 64 + tokL) * 4];
    float v0 = s0.x + s1.x + s2.x + s3.x + bg2[0];
    float v1 = s0.y + s1.y + s2.y + s3.y + bg2[1];
    float v2 = s0.z + s1.z + s2.z + s3.z + bg2[2];
    float v3 = s0.w + s1.w + s2.w + s3.w + bg2[3];
    float gap;
    topk4(v0, v1, v2, v3, gw, gap, i1, i2);
    size_t t = t0 + tokL;
    *(float4*)&out[GW_OFF + t * 4] = gw;
    flagged = (gap < DELTA);
    lgw = gw;
  }
  // compact flagged tokens into global list (wave-level)
  {
    unsigned long long m = __ballot(flagged);
    int cnt = __popcll(m);
    if (cnt){
      unsigned base = 0;
      if (l == 0) base = atomicAdd(cntp, (unsigned)cnt);
      base = __shfl(base, 0, 64);
      if (flagged){
        unsigned rank = (unsigned)__popcll(m & ((1ull << l) - 1ull));
        list[base + rank] = (unsigned)(t0 + tokL) | (i1 << 18) | (i2 << 20);
      }
    }
  }
  // broadcast this token's gw to all lanes of the wave
  float4 gw4;
  gw4.x = __shfl(gw.x, l15, 64);
  gw4.y = __shfl(gw.y, l15, 64);
  gw4.z = __shfl(gw.z, l15, 64);
  gw4.w = __shfl(gw.w, l15, 64);
  // block-local load partial
  #pragma unroll
  for (int m = 1; m < 64; m <<= 1){
    lgw.x += __shfl_xor(lgw.x, m, 64); lgw.y += __shfl_xor(lgw.y, m, 64);
    lgw.z += __shfl_xor(lgw.z, m, 64); lgw.w += __shfl_xor(lgw.w, m, 64);
  }
  if (l == 0) *(float4*)&lsum[w * 4] = lgw;
  __syncthreads();           // also protects gred before hs writes
  if (tid < 4)
    lpart[(size_t)blockIdx.x * 4 + tid] =
        lsum[tid] + lsum[4 + tid] + lsum[8 + tid] + lsum[12 + tid];

  // ================= experts 0..3 + alpha (slot 4) =================
  f32x4 lacc = {0,0,0,0};
  const int key = (tokL & 7) << 4;
  for (int e = 0; e < 5; ++e){
    #pragma unroll
    for (int i = 0; i < 4; ++i)
      #pragma unroll
      for (int tt = 0; tt < 4; ++tt){
        acc[i][tt][0]=0.f; acc[i][tt][1]=0.f; acc[i][tt][2]=0.f; acc[i][tt][3]=0.f;
      }
    run_l1(W1F + (size_t)e * 65536, xsb, w, l, l15, lq, acc);

    const float* b1p = (e < 4) ? (be1 + e * 256) : ba1;
    f32x4 d2a = {0,0,0,0}, d2b = {0,0,0,0};
    #pragma unroll
    for (int p = 0; p < 2; ++p){
      // write hs half: h-tiles w+4i for i = 2p, 2p+1 (global cols [128p,128p+128))
      #pragma unroll
      for (int ii = 0; ii < 2; ++ii){
        int i = 2 * p + ii;
        int hbg = (w + 4 * i) * 16 + lq * 4;
        float4 b4 = *(const float4*)&b1p[hbg];
        int lc2 = (hbg - p * 128) * 2;
        #pragma unroll
        for (int tt = 0; tt < 4; ++tt){
          f16x4 hv = pk4(gelu_fast(acc[i][tt][0] + b4.x),
                         gelu_fast(acc[i][tt][1] + b4.y),
                         gelu_fast(acc[i][tt][2] + b4.z),
                         gelu_fast(acc[i][tt][3] + b4.w));
          int lt = tt * 16 + l15;
          *(f16x4*)(hsb + lt * 256 + (lc2 ^ ((lt & 7) << 4))) = hv;
        }
      }
      __syncthreads();
      // L2 partial: k2 = 4p .. 4p+3, wave reads its own token tile
      #pragma unroll
      for (int k2h = 0; k2h < 4; ++k2h){
        int k2 = 4 * p + k2h;
        f16x8 a2 = *(const f16x8*)&W2F[((size_t)(e * 8 + k2) * 64 + l) * 8];
        f16x8 b2 = *(const f16x8*)(hsb + tokL * 256 +
                     (((k2h * 32 + lq * 8) * 2) ^ key));
        if (k2h & 1) d2b = mfma16(a2, b2, d2b);
        else         d2a = mfma16(a2, b2, d2a);
      }
      __syncthreads();
    }
    size_t t = t0 + tokL;
    if (e < 4){
      float gwv = (e == 0) ? gw4.x : (e == 1) ? gw4.y : (e == 2) ? gw4.z : gw4.w;
      #pragma unroll
      for (int r = 0; r < 4; ++r){
        int c = lq * 4 + r;
        float bv = (c < 10) ? be2[e * 10 + c] : 0.0f;
        lacc[r] += gwv * (d2a[r] + d2b[r] + bv);
      }
    } else {
      #pragma unroll
      for (int r = 0; r < 4; ++r){
        int c = lq * 4 + r;
        if (c < 10)
          out[ALPHA_OFF + t * 10 + c] = softplus_fast(d2a[r] + d2b[r] + ba2[c]) + 1e-6f;
      }
    }
  }
  // final logits write
  {
    size_t t = t0 + tokL;
    #pragma unroll
    for (int r = 0; r < 4; ++r){
      int c = lq * 4 + r;
      if (c < 10) out[t * 10 + c] = lacc[r];
    }
  }
}

// ---------------------------------------------------------------------------
// refine: exact fp32 gate for listed tokens; on selection flip also
// recompute logits (all 4 experts, exact gw).
// ---------------------------------------------------------------------------
__global__ __launch_bounds__(256) void refine_kernel(
    const float* __restrict__ x, const float* __restrict__ Wg1,
    const float* __restrict__ bg1, const float* __restrict__ Wg2,
    const float* __restrict__ bg2,
    const float* __restrict__ We1, const float* __restrict__ be1,
    const float* __restrict__ We2, const float* __restrict__ be2,
    const unsigned int* __restrict__ list, const unsigned int* __restrict__ cntp,
    float* __restrict__ out){
  int cnt = (int)*cntp;
  int l = threadIdx.x & 63;
  int hb = l * 4;
  for (int idx = blockIdx.x * 4 + (threadIdx.x >> 6); idx < cnt;
       idx += gridDim.x * 4){
    unsigned ent = list[idx];
    int t = (int)(ent & 0x3FFFFu);
    int oi1 = (ent >> 18) & 3, oi2 = (ent >> 20) & 3;
    const float* xr = x + (size_t)t * 256;
    float a0 = 0.f, a1 = 0.f, a2 = 0.f, a3 = 0.f;
    #pragma unroll 4
    for (int d = 0; d < 256; ++d){
      float xv = xr[d];
      float4 wv = *(const float4*)&Wg1[d * 256 + hb];
      a0 = fmaf(xv, wv.x, a0); a1 = fmaf(xv, wv.y, a1);
      a2 = fmaf(xv, wv.z, a2); a3 = fmaf(xv, wv.w, a3);
    }
    float4 b4 = *(const float4*)&bg1[hb];
    float g0 = gelu_exact(a0 + b4.x), g1 = gelu_exact(a1 + b4.y);
    float g2 = gelu_exact(a2 + b4.z), g3 = gelu_exact(a3 + b4.w);
    float4 w0 = *(const float4*)&Wg2[(hb + 0) * 4];
    float4 w1 = *(const float4*)&Wg2[(hb + 1) * 4];
    float4 w2 = *(const float4*)&Wg2[(hb + 2) * 4];
    float4 w3 = *(const float4*)&Wg2[(hb + 3) * 4];
    float p0 = g0 * w0.x + g1 * w1.x + g2 * w2.x + g3 * w3.x;
    float p1 = g0 * w0.y + g1 * w1.y + g2 * w2.y + g3 * w3.y;
    float p2 = g0 * w0.z + g1 * w1.z + g2 * w2.z + g3 * w3.z;
    float p3 = g0 * w0.w + g1 * w1.w + g2 * w2.w + g3 * w3.w;
    #pragma unroll
    for (int m = 1; m < 64; m <<= 1){
      p0 += __shfl_xor(p0, m, 64); p1 += __shfl_xor(p1, m, 64);
      p2 += __shfl_xor(p2, m, 64); p3 += __shfl_xor(p3, m, 64);
    }
    float4 gw; float gap; int i1, i2;
    topk4(p0 + bg2[0], p1 + bg2[1], p2 + bg2[2], p3 + bg2[3], gw, gap, i1, i2);
    if (l == 0) *(float4*)&out[GW_OFF + (size_t)t * 4] = gw;
    int oldset = (1 << oi1) | (1 << oi2);
    int newset = (1 << i1) | (1 << i2);
    if (oldset != newset){
      float lg[10];
      #pragma unroll
      for (int c = 0; c < 10; ++c) lg[c] = 0.f;
      for (int e = 0; e < 4; ++e){
        float gwe = (e == 0) ? gw.x : (e == 1) ? gw.y : (e == 2) ? gw.z : gw.w;
        float c0 = 0.f, c1 = 0.f, c2 = 0.f, c3 = 0.f;
        #pragma unroll 4
        for (int d = 0; d < 256; ++d){
          float xv = xr[d];
          float4 wv = *(const float4*)&We1[e * 65536 + d * 256 + hb];
          c0 = fmaf(xv, wv.x, c0); c1 = fmaf(xv, wv.y, c1);
          c2 = fmaf(xv, wv.z, c2); c3 = fmaf(xv, wv.w, c3);
        }
        float4 be = *(const float4*)&be1[e * 256 + hb];
        float h[4];
        h[0] = gelu_exact(c0 + be.x); h[1] = gelu_exact(c1 + be.y);
        h[2] = gelu_exact(c2 + be.z); h[3] = gelu_exact(c3 + be.w);
        #pragma unroll
        for (int r = 0; r < 4; ++r){
          const float* w2p = &We2[e * 2560 + (hb + r) * 10];
          #pragma unroll
          for (int c = 0; c < 10; ++c) lg[c] += gwe * (h[r] * w2p[c]);
        }
      }
      #pragma unroll
      for (int m = 1; m < 64; m <<= 1)
        #pragma unroll
        for (int c = 0; c < 10; ++c) lg[c] += __shfl_xor(lg[c], m, 64);
      if (l == 0){
        #pragma unroll
        for (int c = 0; c < 10; ++c)
          out[(size_t)t * 10 + c] = lg[c] + gw.x * be2[c] + gw.y * be2[10 + c]
                                         + gw.z * be2[20 + c] + gw.w * be2[30 + c];
      }
    }
  }
}

// deterministic tree reduce of 4096x4 partials -> load[4]
__global__ void reduce_load(const float* __restrict__ lpart, float* __restrict__ out){
  __shared__ float red[64][4];
  int tid = threadIdx.x;
  int e = tid & 3, ch = tid >> 2;
  float s = 0.0f;
  for (int i = 0; i < 64; ++i) s += lpart[(size_t)(ch * 64 + i) * 4 + e];
  red[ch][e] = s;
  __syncthreads();
  if (tid < 4){
    float t = 0.0f;
    for (int c = 0; c < 64; ++c) t += red[c][tid];
    out[LOAD_OFF + tid] = t;
  }
}

// ---------------------------------------------------------------------------
extern "C" void kernel_launch(void* const* d_in, const int* in_sizes, int n_in,
                              void* d_out, int out_size, void* d_ws, size_t ws_size,
                              hipStream_t stream){
  const float* x   = (const float*)d_in[0];
  const float* Wg1 = (const float*)d_in[1];
  const float* bg1 = (const float*)d_in[2];
  const float* Wg2 = (const float*)d_in[3];
  const float* bg2 = (const float*)d_in[4];
  const float* We1 = (const float*)d_in[5];
  const float* be1 = (const float*)d_in[6];
  const float* We2 = (const float*)d_in[7];
  const float* be2 = (const float*)d_in[8];
  const float* Wa1 = (const float*)d_in[9];
  const float* ba1 = (const float*)d_in[10];
  const float* Wa2 = (const float*)d_in[11];
  const float* ba2 = (const float*)d_in[12];
  float* out = (float*)d_out;

  _Float16* W1F       = (_Float16*)((char*)d_ws + W1F_OFF);
  _Float16* W2F       = (_Float16*)((char*)d_ws + W2F_OFF);
  unsigned int* cntp  = (unsigned int*)((char*)d_ws + CNT_OFF);
  unsigned int* list  = (unsigned int*)((char*)d_ws + LIST_OFF);
  float* lpart        = (float*)((char*)d_ws + LPART_OFF);

  hipLaunchKernelGGL(prep_w1f, dim3(192), dim3(256), 0, stream, We1, Wa1, Wg1, W1F);
  hipLaunchKernelGGL(prep_w2f, dim3(12),  dim3(256), 0, stream, We2, Wa2, Wg2, W2F, cntp);
  hipLaunchKernelGGL(fused_kernel, dim3(4096), dim3(256), 0, stream,
                     x, W1F, W2F, bg1, Wg2, bg2, be1, be2, ba1, ba2,
                     out, list, cntp, lpart);
  hipLaunchKernelGGL(refine_kernel, dim3(256), dim3(256), 0, stream,
                     x, Wg1, bg1, Wg2, bg2, We1, be1, We2, be2, list, cntp, out);
  hipLaunchKernelGGL(reduce_load, dim3(1), dim3(256), 0, stream, lpart, out);
}

// Round 6
// 579.892 us; speedup vs baseline: 2.3357x; 1.1527x over previous
//
#include <hip/hip_runtime.h>
#include <hip/hip_bf16.h>

// ============================================================================
// ASTRAMoE v6: fused pass, fp16 MFMA, 8-wave blocks for 16 waves/CU.
//   All 6 slots (gate, 4 experts, alpha) share one uniform pipeline:
//   L1 MFMA (W1F from L2 cache, barrier-free) -> gelu_fast -> hs (LDS,
//   swizzled) -> L2 MFMA (W2F). Gate slot: topk at lq==0 lanes from d2,
//   gw broadcast via shfl; flag gap<0.02 -> exact fp32 refine after.
//   Wave w: h-strip tiles {w, w+8}; L2 token tile w&3 (dup across w>>2).
// d_out (fp32): logits[N*10] | alpha[N*10] | gate_weights[N*4] | load[4]
// ============================================================================

typedef _Float16 f16x8 __attribute__((ext_vector_type(8)));
typedef _Float16 f16x4 __attribute__((ext_vector_type(4)));
typedef float    f32x4 __attribute__((ext_vector_type(4)));

static constexpr int    NTOK      = 262144;
static constexpr size_t ALPHA_OFF = (size_t)NTOK * 10;
static constexpr size_t GW_OFF    = (size_t)2 * NTOK * 10;
static constexpr size_t LOAD_OFF  = GW_OFF + (size_t)NTOK * 4;

// ws layout (bytes)
static constexpr size_t W1F_OFF   = 0;          // 6*65536 halfs = 786432
static constexpr size_t W2F_OFF   = 786432;     // 6*4096 halfs  = 49152
static constexpr size_t CNT_OFF   = 835584;     // u32 counter (64 B slot)
static constexpr size_t LIST_OFF  = 835648;     // 262144 u32   = 1 MB
static constexpr size_t LPART_OFF = 1884224;    // 4096*4 f32   = 64 KB

static constexpr float DELTA = 0.02f;

__device__ __forceinline__ float gelu_exact(float v){
  return 0.5f * v * (1.0f + erff(v * 0.7071067811865475f));
}
__device__ __forceinline__ float gelu_fast(float v){
  float t = v * v;
  float p = __builtin_fmaf(0.0713548162726f, t, 1.5957691216057f);
  float z = __expf(v * p);
  float r = __builtin_amdgcn_rcpf(z + 1.0f);
  return v - v * r;
}
__device__ __forceinline__ float softplus_fast(float v){
  float z = __expf(v);
  float l = __logf(1.0f + z);
  return (v > 15.0f) ? v : l;
}
__device__ __forceinline__ f32x4 mfma16(f16x8 a, f16x8 b, f32x4 c){
  return __builtin_amdgcn_mfma_f32_16x16x32_f16(a, b, c, 0, 0, 0);
}
__device__ __forceinline__ f16x8 pk8(float4 a, float4 b){
  union { f16x8 v; unsigned u[4]; } r;
  r.u[0] = __builtin_bit_cast(unsigned, __builtin_amdgcn_cvt_pkrtz(a.x, a.y));
  r.u[1] = __builtin_bit_cast(unsigned, __builtin_amdgcn_cvt_pkrtz(a.z, a.w));
  r.u[2] = __builtin_bit_cast(unsigned, __builtin_amdgcn_cvt_pkrtz(b.x, b.y));
  r.u[3] = __builtin_bit_cast(unsigned, __builtin_amdgcn_cvt_pkrtz(b.z, b.w));
  return r.v;
}
__device__ __forceinline__ f16x4 pk4(float a, float b, float c, float d){
  union { f16x4 v; unsigned u[2]; } r;
  r.u[0] = __builtin_bit_cast(unsigned, __builtin_amdgcn_cvt_pkrtz(a, b));
  r.u[1] = __builtin_bit_cast(unsigned, __builtin_amdgcn_cvt_pkrtz(c, d));
  return r.v;
}

// exact top-2 (lowest index wins ties, matches jax.lax.top_k) + scatter-softmax
__device__ __forceinline__ void topk4(float v0, float v1, float v2, float v3,
                                      float4& gw, float& gap, int& i1, int& i2){
  float m1 = fmaxf(fmaxf(v0, v1), fmaxf(v2, v3));
  i1 = (v0 == m1) ? 0 : (v1 == m1) ? 1 : (v2 == m1) ? 2 : 3;
  float m2 = 0.f; i2 = -1;
  if (0 != i1){ m2 = v0; i2 = 0; }
  if (1 != i1 && (i2 < 0 || v1 > m2)){ m2 = v1; i2 = 1; }
  if (2 != i1 && (i2 < 0 || v2 > m2)){ m2 = v2; i2 = 2; }
  if (3 != i1 && (i2 < 0 || v3 > m2)){ m2 = v3; i2 = 3; }
  float m3 = -3.0e38f;
  if (0 != i1 && 0 != i2) m3 = fmaxf(m3, v0);
  if (1 != i1 && 1 != i2) m3 = fmaxf(m3, v1);
  if (2 != i1 && 2 != i2) m3 = fmaxf(m3, v2);
  if (3 != i1 && 3 != i2) m3 = fmaxf(m3, v3);
  gap = m2 - m3;
  float mm = fmaxf(m1, 0.0f);
  float s0 = (0 == i1 || 0 == i2) ? v0 : 0.0f;
  float s1 = (1 == i1 || 1 == i2) ? v1 : 0.0f;
  float s2 = (2 == i1 || 2 == i2) ? v2 : 0.0f;
  float s3 = (3 == i1 || 3 == i2) ? v3 : 0.0f;
  float e0 = expf(s0 - mm), e1 = expf(s1 - mm), e2 = expf(s2 - mm), e3 = expf(s3 - mm);
  float inv = 1.0f / (e0 + e1 + e2 + e3);
  gw.x = e0 * inv; gw.y = e1 * inv; gw.z = e2 * inv; gw.w = e3 * inv;
}

// ---------------------------------------------------------------------------
// prep: W1F frag-linear fp16 A-layout: [e(6)][kc(8)][ht(16)][lane(64)][8]
//   value = W1^T[h = ht*16 + (l&15)][d = kc*32 + (l>>4)*8 + j]
// ---------------------------------------------------------------------------
__global__ void prep_w1f(const float* __restrict__ We1, const float* __restrict__ Wa1,
                         const float* __restrict__ Wg1, _Float16* __restrict__ W1F){
  int idx = blockIdx.x * 256 + threadIdx.x;          // < 49152
  int e = idx >> 13;
  int r = idx & 8191;
  int kc = r >> 10;
  int entry = r & 1023;
  int ht = entry >> 6, ll = entry & 63;
  int h = ht * 16 + (ll & 15);
  int d0 = kc * 32 + ((ll >> 4) << 3);
  f16x8 o;
  #pragma unroll
  for (int j = 0; j < 8; ++j){
    int d = d0 + j;
    float v;
    if (e < 4)       v = We1[e * 65536 + d * 256 + h];
    else if (e == 4) v = Wa1[d * 256 + h];
    else             v = Wg1[d * 256 + h];
    o[j] = (_Float16)v;
  }
  *(f16x8*)&W1F[(size_t)idx * 8] = o;
}

// prep: W2F frag-linear fp16 A-layout: [e(6)][kc2(8)][lane(64)][8]; zero counter
__global__ void prep_w2f(const float* __restrict__ We2, const float* __restrict__ Wa2,
                         const float* __restrict__ Wg2, _Float16* __restrict__ W2F,
                         unsigned int* __restrict__ cntp){
  if (blockIdx.x == 0 && threadIdx.x == 0) *cntp = 0;
  int idx = blockIdx.x * 256 + threadIdx.x;          // < 3072
  int e = idx >> 9;
  int r = idx & 511;
  int k2 = r >> 6, ll = r & 63;
  int c = ll & 15;
  int h0 = k2 * 32 + ((ll >> 4) << 3);
  f16x8 o;
  #pragma unroll
  for (int j = 0; j < 8; ++j){
    int h = h0 + j;
    float v = 0.0f;
    if (e < 4){ if (c < 10) v = We2[e * 2560 + h * 10 + c]; }
    else if (e == 4){ if (c < 10) v = Wa2[h * 10 + c]; }
    else { if (c < 4) v = Wg2[h * 4 + c]; }
    o[j] = (_Float16)v;
  }
  *(f16x8*)&W2F[(size_t)idx * 8] = o;
}

// ---------------------------------------------------------------------------
// fused kernel. 512 threads (8 waves), 64 tokens/block, 4096 blocks.
// Wave w: L1 h-strip tiles {w, w+8} (32 h) over all 64 tokens (acc[2][4]);
// L2/epilogue token tile (w&3), duplicated across w>>2, only w<4 write.
// LDS: xs 32K (swizzled fp16 x) | hs 32K ([64 tok][256 h] swizzled) | lsum
//   = 64.1 KB -> 2 blocks/CU = 16 waves/CU.
// ---------------------------------------------------------------------------
__device__ __forceinline__ void run_l1(const _Float16* __restrict__ w1s,
                                       const unsigned char* __restrict__ xsb,
                                       int w, int l, int l15, int lq,
                                       f32x4 acc[2][4]){
  #pragma unroll
  for (int kc = 0; kc < 8; ++kc){
    f16x8 af[2], bf[4];
    #pragma unroll
    for (int i = 0; i < 2; ++i)
      af[i] = *(const f16x8*)&w1s[(size_t)kc * 8192 + (w + 8 * i) * 512 + l * 8];
    #pragma unroll
    for (int tt = 0; tt < 4; ++tt){
      int lt = tt * 16 + l15;
      bf[tt] = *(const f16x8*)(xsb + lt * 512 +
                 ((kc * 64 + lq * 16) ^ ((lt & 7) << 4)));
    }
    __builtin_amdgcn_s_setprio(1);
    #pragma unroll
    for (int i = 0; i < 2; ++i)
      #pragma unroll
      for (int tt = 0; tt < 4; ++tt)
        acc[i][tt] = mfma16(af[i], bf[tt], acc[i][tt]);
    __builtin_amdgcn_s_setprio(0);
  }
}

__global__ __launch_bounds__(512, 4) void fused_kernel(
    const float* __restrict__ x,
    const _Float16* __restrict__ W1F, const _Float16* __restrict__ W2F,
    const float* __restrict__ bg1, const float* __restrict__ bg2,
    const float* __restrict__ be1, const float* __restrict__ be2,
    const float* __restrict__ ba1, const float* __restrict__ ba2,
    float* __restrict__ out, unsigned int* __restrict__ list,
    unsigned int* __restrict__ cntp, float* __restrict__ lpart){
  __shared__ __align__(16) unsigned char lds[65600];
  unsigned char* xsb = lds;                         // 32 KB
  unsigned char* hsb = lds + 32768;                 // 32 KB
  float*        lsum = (float*)(lds + 65536);       // 16 floats

  const int tid = threadIdx.x;
  const int w = tid >> 6, l = tid & 63;
  const int l15 = l & 15, lq = l >> 4;
  const size_t t0 = (size_t)blockIdx.x * 64;
  const int tokL = (w & 3) * 16 + l15;              // L2 token within block
  const int key  = (tokL & 7) << 4;

  // ---- stage x -> fp16 swizzled LDS (coalesced 32B/lane loads) ----
  {
    int d = (tid & 31) * 8;
    #pragma unroll
    for (int q = 0; q < 4; ++q){
      int tk = q * 16 + (tid >> 5);
      const float* xp = x + (t0 + tk) * 256 + d;
      float4 f0 = *(const float4*)xp;
      float4 f1 = *(const float4*)(xp + 4);
      *(f16x8*)(xsb + tk * 512 + ((d * 2) ^ ((tk & 7) << 4))) = pk8(f0, f1);
    }
  }
  __syncthreads();

  f32x4 lacc = {0,0,0,0};
  float4 gw4 = {0,0,0,0};

  for (int s = 0; s < 6; ++s){
    const int e = (s == 0) ? 5 : (s - 1);   // gate first, then experts, alpha
    f32x4 acc[2][4];
    #pragma unroll
    for (int i = 0; i < 2; ++i)
      #pragma unroll
      for (int tt = 0; tt < 4; ++tt){
        acc[i][tt][0]=0.f; acc[i][tt][1]=0.f; acc[i][tt][2]=0.f; acc[i][tt][3]=0.f;
      }
    run_l1(W1F + (size_t)e * 65536, xsb, w, l, l15, lq, acc);
    __syncthreads();   // prior slot's hs readers are done

    // epilogue L1: bias + fast GELU -> hs
    const float* b1p = (e == 5) ? bg1 : (e < 4 ? be1 + e * 256 : ba1);
    #pragma unroll
    for (int i = 0; i < 2; ++i){
      int hb = (w + 8 * i) * 16 + lq * 4;
      float4 b4 = *(const float4*)&b1p[hb];
      #pragma unroll
      for (int tt = 0; tt < 4; ++tt){
        f16x4 hv = pk4(gelu_fast(acc[i][tt][0] + b4.x),
                       gelu_fast(acc[i][tt][1] + b4.y),
                       gelu_fast(acc[i][tt][2] + b4.z),
                       gelu_fast(acc[i][tt][3] + b4.w));
        int lt = tt * 16 + l15;
        *(f16x4*)(hsb + lt * 512 + ((hb * 2) ^ ((lt & 7) << 4))) = hv;
      }
    }
    __syncthreads();   // hs ready

    // L2: token tile w&3 (duplicated across w>>2)
    f32x4 d2 = {0,0,0,0};
    #pragma unroll
    for (int k2 = 0; k2 < 8; ++k2){
      f16x8 a2 = *(const f16x8*)&W2F[((size_t)(e * 8 + k2) * 64 + l) * 8];
      f16x8 b2 = *(const f16x8*)(hsb + tokL * 512 + ((k2 * 64 + lq * 16) ^ key));
      d2 = mfma16(a2, b2, d2);
    }

    if (s == 0){
      // ---- gate epilogue: topk at lq==0 (d2[r] = logit class r) ----
      float4 gw = {0,0,0,0};
      float4 lgw = {0,0,0,0};
      int i1 = 0, i2 = 0;
      bool flagged = false;
      if (lq == 0){
        float v0 = d2[0] + bg2[0], v1 = d2[1] + bg2[1];
        float v2 = d2[2] + bg2[2], v3 = d2[3] + bg2[3];
        float gap;
        topk4(v0, v1, v2, v3, gw, gap, i1, i2);
        if (w < 4){
          size_t t = t0 + tokL;
          *(float4*)&out[GW_OFF + t * 4] = gw;
          flagged = (gap < DELTA);
          lgw = gw;
        }
      }
      // broadcast token's gw to all lanes (source lanes 0..15 have lq==0)
      gw4.x = __shfl(gw.x, l15, 64);
      gw4.y = __shfl(gw.y, l15, 64);
      gw4.z = __shfl(gw.z, l15, 64);
      gw4.w = __shfl(gw.w, l15, 64);
      if (w < 4){
        // compact flagged tokens into global list (wave-level)
        unsigned long long m = __ballot(flagged);
        int cnt = __popcll(m);
        if (cnt){
          unsigned base = 0;
          if (l == 0) base = atomicAdd(cntp, (unsigned)cnt);
          base = __shfl(base, 0, 64);
          if (flagged){
            unsigned rank = (unsigned)__popcll(m & ((1ull << l) - 1ull));
            list[base + rank] = (unsigned)(t0 + tokL) | (i1 << 18) | (i2 << 20);
          }
        }
        // block-local load partial
        #pragma unroll
        for (int mm = 1; mm < 64; mm <<= 1){
          lgw.x += __shfl_xor(lgw.x, mm, 64); lgw.y += __shfl_xor(lgw.y, mm, 64);
          lgw.z += __shfl_xor(lgw.z, mm, 64); lgw.w += __shfl_xor(lgw.w, mm, 64);
        }
        if (l == 0) *(float4*)&lsum[w * 4] = lgw;
      }
      __syncthreads();
      if (tid < 4)
        lpart[(size_t)blockIdx.x * 4 + tid] =
            lsum[tid] + lsum[4 + tid] + lsum[8 + tid] + lsum[12 + tid];
    } else if (e < 4){
      float gwv = (e == 0) ? gw4.x : (e == 1) ? gw4.y : (e == 2) ? gw4.z : gw4.w;
      #pragma unroll
      for (int r = 0; r < 4; ++r){
        int c = lq * 4 + r;
        float bv = (c < 10) ? be2[e * 10 + c] : 0.0f;
        lacc[r] += gwv * (d2[r] + bv);
      }
    } else {
      if (w < 4){
        size_t t = t0 + tokL;
        #pragma unroll
        for (int r = 0; r < 4; ++r){
          int c = lq * 4 + r;
          if (c < 10)
            out[ALPHA_OFF + t * 10 + c] = softplus_fast(d2[r] + ba2[c]) + 1e-6f;
        }
      }
    }
  }
  // final logits write
  if (w < 4){
    size_t t = t0 + tokL;
    #pragma unroll
    for (int r = 0; r < 4; ++r){
      int c = lq * 4 + r;
      if (c < 10) out[t * 10 + c] = lacc[r];
    }
  }
}

// ---------------------------------------------------------------------------
// refine: exact fp32 gate for listed tokens; on selection flip also
// recompute logits (all 4 experts, exact gw).
// ---------------------------------------------------------------------------
__global__ __launch_bounds__(256) void refine_kernel(
    const float* __restrict__ x, const float* __restrict__ Wg1,
    const float* __restrict__ bg1, const float* __restrict__ Wg2,
    const float* __restrict__ bg2,
    const float* __restrict__ We1, const float* __restrict__ be1,
    const float* __restrict__ We2, const float* __restrict__ be2,
    const unsigned int* __restrict__ list, const unsigned int* __restrict__ cntp,
    float* __restrict__ out){
  int cnt = (int)*cntp;
  int l = threadIdx.x & 63;
  int hb = l * 4;
  for (int idx = blockIdx.x * 4 + (threadIdx.x >> 6); idx < cnt;
       idx += gridDim.x * 4){
    unsigned ent = list[idx];
    int t = (int)(ent & 0x3FFFFu);
    int oi1 = (ent >> 18) & 3, oi2 = (ent >> 20) & 3;
    const float* xr = x + (size_t)t * 256;
    float a0 = 0.f, a1 = 0.f, a2 = 0.f, a3 = 0.f;
    #pragma unroll 8
    for (int d = 0; d < 256; ++d){
      float xv = xr[d];
      float4 wv = *(const float4*)&Wg1[d * 256 + hb];
      a0 = fmaf(xv, wv.x, a0); a1 = fmaf(xv, wv.y, a1);
      a2 = fmaf(xv, wv.z, a2); a3 = fmaf(xv, wv.w, a3);
    }
    float4 b4 = *(const float4*)&bg1[hb];
    float g0 = gelu_exact(a0 + b4.x), g1 = gelu_exact(a1 + b4.y);
    float g2 = gelu_exact(a2 + b4.z), g3 = gelu_exact(a3 + b4.w);
    float4 w0 = *(const float4*)&Wg2[(hb + 0) * 4];
    float4 w1 = *(const float4*)&Wg2[(hb + 1) * 4];
    float4 w2 = *(const float4*)&Wg2[(hb + 2) * 4];
    float4 w3 = *(const float4*)&Wg2[(hb + 3) * 4];
    float p0 = g0 * w0.x + g1 * w1.x + g2 * w2.x + g3 * w3.x;
    float p1 = g0 * w0.y + g1 * w1.y + g2 * w2.y + g3 * w3.y;
    float p2 = g0 * w0.z + g1 * w1.z + g2 * w2.z + g3 * w3.z;
    float p3 = g0 * w0.w + g1 * w1.w + g2 * w2.w + g3 * w3.w;
    #pragma unroll
    for (int m = 1; m < 64; m <<= 1){
      p0 += __shfl_xor(p0, m, 64); p1 += __shfl_xor(p1, m, 64);
      p2 += __shfl_xor(p2, m, 64); p3 += __shfl_xor(p3, m, 64);
    }
    float4 gw; float gap; int i1, i2;
    topk4(p0 + bg2[0], p1 + bg2[1], p2 + bg2[2], p3 + bg2[3], gw, gap, i1, i2);
    if (l == 0) *(float4*)&out[GW_OFF + (size_t)t * 4] = gw;
    int oldset = (1 << oi1) | (1 << oi2);
    int newset = (1 << i1) | (1 << i2);
    if (oldset != newset){
      float lg[10];
      #pragma unroll
      for (int c = 0; c < 10; ++c) lg[c] = 0.f;
      for (int e = 0; e < 4; ++e){
        float gwe = (e == 0) ? gw.x : (e == 1) ? gw.y : (e == 2) ? gw.z : gw.w;
        float c0 = 0.f, c1 = 0.f, c2 = 0.f, c3 = 0.f;
        #pragma unroll 8
        for (int d = 0; d < 256; ++d){
          float xv = xr[d];
          float4 wv = *(const float4*)&We1[e * 65536 + d * 256 + hb];
          c0 = fmaf(xv, wv.x, c0); c1 = fmaf(xv, wv.y, c1);
          c2 = fmaf(xv, wv.z, c2); c3 = fmaf(xv, wv.w, c3);
        }
        float4 be = *(const float4*)&be1[e * 256 + hb];
        float h[4];
        h[0] = gelu_exact(c0 + be.x); h[1] = gelu_exact(c1 + be.y);
        h[2] = gelu_exact(c2 + be.z); h[3] = gelu_exact(c3 + be.w);
        #pragma unroll
        for (int r = 0; r < 4; ++r){
          const float* w2p = &We2[e * 2560 + (hb + r) * 10];
          #pragma unroll
          for (int c = 0; c < 10; ++c) lg[c] += gwe * (h[r] * w2p[c]);
        }
      }
      #pragma unroll
      for (int m = 1; m < 64; m <<= 1)
        #pragma unroll
        for (int c = 0; c < 10; ++c) lg[c] += __shfl_xor(lg[c], m, 64);
      if (l == 0){
        #pragma unroll
        for (int c = 0; c < 10; ++c)
          out[(size_t)t * 10 + c] = lg[c] + gw.x * be2[c] + gw.y * be2[10 + c]
                                         + gw.z * be2[20 + c] + gw.w * be2[30 + c];
      }
    }
  }
}

// deterministic tree reduce of 4096x4 partials -> load[4]
__global__ void reduce_load(const float* __restrict__ lpart, float* __restrict__ out){
  __shared__ float red[64][4];
  int tid = threadIdx.x;
  int e = tid & 3, ch = tid >> 2;
  float s = 0.0f;
  for (int i = 0; i < 64; ++i) s += lpart[(size_t)(ch * 64 + i) * 4 + e];
  red[ch][e] = s;
  __syncthreads();
  if (tid < 4){
    float t = 0.0f;
    for (int c = 0; c < 64; ++c) t += red[c][tid];
    out[LOAD_OFF + tid] = t;
  }
}

// ---------------------------------------------------------------------------
extern "C" void kernel_launch(void* const* d_in, const int* in_sizes, int n_in,
                              void* d_out, int out_size, void* d_ws, size_t ws_size,
                              hipStream_t stream){
  const float* x   = (const float*)d_in[0];
  const float* Wg1 = (const float*)d_in[1];
  const float* bg1 = (const float*)d_in[2];
  const float* Wg2 = (const float*)d_in[3];
  const float* bg2 = (const float*)d_in[4];
  const float* We1 = (const float*)d_in[5];
  const float* be1 = (const float*)d_in[6];
  const float* We2 = (const float*)d_in[7];
  const float* be2 = (const float*)d_in[8];
  const float* Wa1 = (const float*)d_in[9];
  const float* ba1 = (const float*)d_in[10];
  const float* Wa2 = (const float*)d_in[11];
  const float* ba2 = (const float*)d_in[12];
  float* out = (float*)d_out;

  _Float16* W1F       = (_Float16*)((char*)d_ws + W1F_OFF);
  _Float16* W2F       = (_Float16*)((char*)d_ws + W2F_OFF);
  unsigned int* cntp  = (unsigned int*)((char*)d_ws + CNT_OFF);
  unsigned int* list  = (unsigned int*)((char*)d_ws + LIST_OFF);
  float* lpart        = (float*)((char*)d_ws + LPART_OFF);

  hipLaunchKernelGGL(prep_w1f, dim3(192), dim3(256), 0, stream, We1, Wa1, Wg1, W1F);
  hipLaunchKernelGGL(prep_w2f, dim3(12),  dim3(256), 0, stream, We2, Wa2, Wg2, W2F, cntp);
  hipLaunchKernelGGL(fused_kernel, dim3(4096), dim3(512), 0, stream,
                     x, W1F, W2F, bg1, bg2, be1, be2, ba1, ba2,
                     out, list, cntp, lpart);
  hipLaunchKernelGGL(refine_kernel, dim3(1024), dim3(256), 0, stream,
                     x, Wg1, bg1, Wg2, bg2, We1, be1, We2, be2, list, cntp, out);
  hipLaunchKernelGGL(reduce_load, dim3(1), dim3(256), 0, stream, lpart, out);
}